// Round 4
// baseline (2070.883 us; speedup 1.0000x reference)
//
#include <hip/hip_runtime.h>

typedef __attribute__((ext_vector_type(4))) float f32x4;
typedef unsigned char u8;

#define BIG_NEG -1000000000.0f

static constexpr int B_  = 256;
static constexpr int SX_ = 34;
static constexpr int SY_ = 34;
static constexpr int IND = 66;   // IN_DIM
static constexpr int OP_ = 80;   // padded OUT_DIM (65 -> 80)

__device__ __forceinline__ f32x4 mfma_fp8(long a, long b, f32x4 c) {
  return __builtin_amdgcn_mfma_f32_16x16x32_fp8_fp8(a, b, c, 0, 0, 0);
}
__device__ __forceinline__ float sigm(float x)  { return 1.0f / (1.0f + __expf(-x)); }
__device__ __forceinline__ float tanhx(float x) { return 2.0f * sigm(2.0f * x) - 1.0f; }
template <bool HI>
__device__ __forceinline__ unsigned pk2(float a, float b, unsigned old) {
  return __builtin_amdgcn_cvt_pk_fp8_f32(a, b, (int)old, HI);
}

// ---------------------------------------------------------------------------
// prep kernels
// ---------------------------------------------------------------------------
__global__ void decode_tokens(const float* __restrict__ src,
                              const float* __restrict__ tgt,
                              int* __restrict__ tok_x, int* __restrict__ tok_y) {
  int idx = blockIdx.x * 256 + threadIdx.x;
  const int half = SX_ * B_;
  if (idx >= 2 * half) return;
  const float* base = (idx < half) ? src : tgt;
  int* outp         = (idx < half) ? tok_x : tok_y;
  int k = (idx < half) ? idx : idx - half;
  const float* p = base + (size_t)k * IND;
  int tok = -1;
  for (int v = 0; v < IND; ++v) if (p[v] > 0.5f) tok = v;
  outp[k] = tok;
}

// Wcat: fp8 [160][1024]; rows 0..79 = W_sub (padded), 80..159 = W_ins
__global__ void pad_head_w(const float* __restrict__ Wsub, const float* __restrict__ Wins,
                           u8* __restrict__ Wcat) {
  int widx = blockIdx.x * 256 + threadIdx.x;  // one 4-byte word
  if (widx >= 160 * 256) return;
  int row = widx >> 8;
  int wc  = widx & 255;
  int srow = row < 80 ? row : row - 80;
  const float* W = row < 80 ? Wsub : Wins;
  float f0 = 0.f, f1 = 0.f, f2 = 0.f, f3 = 0.f;
  if (srow < 65) {
    const float* p = W + (size_t)srow * 1024 + wc * 4;
    f0 = p[0]; f1 = p[1]; f2 = p[2]; f3 = p[3];
  }
  unsigned w = pk2<false>(f0, f1, 0);
  w = pk2<true>(f2, f3, w);
  ((unsigned*)Wcat)[widx] = w;
}

// ---------------------------------------------------------------------------
// persistent LSTM: 256 blocks x 256 thr (1/CU).
//   [0,64) fwd H=512 | [64,128) rev H=512 | [128,256) modern H=1024
// Block owns 8 hidden x 4 gates. Whh (fp8), Wih slice, bias, tokens all in
// LDS (staged once) -> per-step fence invalidation only re-fetches h.
// h stored as fp8. 3 independent flag-array barriers (per role).
// ---------------------------------------------------------------------------
template <int HH>
__device__ __forceinline__ void run_steps(
    u8* __restrict__ hall, bool rev_role,
    const u8* __restrict__ wslice, const float* __restrict__ wih_lds,
    const float* __restrict__ bias_lds, const signed char* __restrict__ tok_lds,
    u8* __restrict__ hstage, unsigned* __restrict__ flags,
    int gbase, int gidx, int gcount, int h0) {
  const int lane = threadIdx.x & 63, wave = threadIdx.x >> 6;
  const int lo = lane & 15, q = lane >> 4, sw = lo & 7;
  const bool hi = (lo >= 8);
  constexpr int NK = HH / 32;
  constexpr int PF = 8;

  float creg[4][2] = {{0.f,0.f},{0.f,0.f},{0.f,0.f},{0.f,0.f}};

  const u8* wb0 = wslice + lo * HH;
  const u8* wb1 = wslice + (16 + lo) * HH;

  for (int t = 0; t < 34; ++t) {
    int tpos = rev_role ? (33 - t) : t;
    f32x4 acc[4][2];
#pragma unroll
    for (int mt = 0; mt < 4; ++mt) {
      acc[mt][0] = (f32x4){0.f,0.f,0.f,0.f};
      acc[mt][1] = (f32x4){0.f,0.f,0.f,0.f};
    }

    if (t > 0) {
      const u8* hsrc = hall + (size_t)t * (256 * HH);
      const u8* ap[4];
#pragma unroll
      for (int mt = 0; mt < 4; ++mt)
        ap[mt] = hsrc + (size_t)(wave * 64 + mt * 16 + lo) * HH + q * 8;

      long areg[PF][4];
#pragma unroll
      for (int p = 0; p < PF; ++p)
#pragma unroll
        for (int mt = 0; mt < 4; ++mt)
          areg[p][mt] = *(const long*)(ap[mt] + p * 32);

#pragma unroll
      for (int i = 0; i < NK; ++i) {
        int off = ((((i * 4) | q) ^ sw) << 3);
        long b0 = *(const long*)(wb0 + off);
        long b1 = *(const long*)(wb1 + off);
#pragma unroll
        for (int mt = 0; mt < 4; ++mt) {
          acc[mt][0] = mfma_fp8(areg[i % PF][mt], b0, acc[mt][0]);
          acc[mt][1] = mfma_fp8(areg[i % PF][mt], b1, acc[mt][1]);
        }
        if (i + PF < NK) {
#pragma unroll
          for (int mt = 0; mt < 4; ++mt)
            areg[i % PF][mt] = *(const long*)(ap[mt] + (i + PF) * 32);
        }
      }
    }

    // epilogue: gates -> h (layout proven in R2; Wih/bias/tok now from LDS)
    const signed char* tokp = tok_lds + tpos * 256;
    const int hh = sw;
#pragma unroll
    for (int mt = 0; mt < 4; ++mt) {
      f32x4 t0 = acc[mt][0], t1 = acc[mt][1];
      f32x4 p0, p1;
#pragma unroll
      for (int c2 = 0; c2 < 4; ++c2) {
        p0[c2] = __shfl_xor(t0[c2], 8, 64);
        p1[c2] = __shfl_xor(t1[c2], 8, 64);
      }
#pragma unroll
      for (int rr = 0; rr < 2; ++rr) {
        int r = (hi ? 2 : 0) + rr;
        float iv = hi ? p0[r] : t0[r];
        float fv = hi ? t0[r] : p0[r];
        float gv = hi ? p1[r] : t1[r];
        float ov = hi ? t1[r] : p1[r];
        int b = wave * 64 + mt * 16 + q * 4 + r;
        int tk = tokp[b];
        if (tk >= 0) {
          iv += wih_lds[(0 * 8 + hh) * 66 + tk];
          fv += wih_lds[(1 * 8 + hh) * 66 + tk];
          gv += wih_lds[(2 * 8 + hh) * 66 + tk];
          ov += wih_lds[(3 * 8 + hh) * 66 + tk];
        }
        iv += bias_lds[hh]; fv += bias_lds[8 + hh];
        gv += bias_lds[16 + hh]; ov += bias_lds[24 + hh];
        float cold = creg[mt][rr];
        float cn = sigm(fv) * cold + sigm(iv) * tanhx(gv);
        float hn = sigm(ov) * tanhx(cn);
        creg[mt][rr] = cn;
        hstage[b * 8 + hh] = (u8)(pk2<false>(hn, hn, 0) & 0xffu);
      }
    }

    __syncthreads();
    {
      u8* hdst = hall + (size_t)(t + 1) * (256 * HH);
      *(unsigned long long*)(hdst + (size_t)threadIdx.x * HH + h0) =
          *(const unsigned long long*)&hstage[threadIdx.x * 8];
    }

    if (t < 33) {
      __threadfence();              // release: drain + wbl2 (per wave)
      __syncthreads();
      if (threadIdx.x == 0)
        __hip_atomic_store(&flags[gbase + gidx], (unsigned)(t + 1),
                           __ATOMIC_RELAXED, __HIP_MEMORY_SCOPE_AGENT);
      if (threadIdx.x < 64) {
        unsigned tgt = (unsigned)(t + 1);
        long long tt0 = __builtin_amdgcn_s_memrealtime();
        for (;;) {
          unsigned v0 = __hip_atomic_load(&flags[gbase + threadIdx.x],
                                          __ATOMIC_RELAXED, __HIP_MEMORY_SCOPE_AGENT);
          unsigned v1 = (gcount == 128)
              ? __hip_atomic_load(&flags[gbase + 64 + threadIdx.x],
                                  __ATOMIC_RELAXED, __HIP_MEMORY_SCOPE_AGENT)
              : tgt;
          if (__ballot((v0 < tgt) || (v1 < tgt)) == 0) break;
          __builtin_amdgcn_s_sleep(2);
          if (__builtin_amdgcn_s_memrealtime() - tt0 > 10000000LL) break;
        }
      }
      __syncthreads();
      __threadfence();              // acquire: inv L1/L2
    }
  }
}

__global__ __launch_bounds__(256, 1) void lstm_persist(
    const int* __restrict__ tok_x, const int* __restrict__ tok_y,
    const float* __restrict__ Wih_f, const float* __restrict__ bf_v, const float* __restrict__ Whh_f,
    const float* __restrict__ Wih_r, const float* __restrict__ br_v, const float* __restrict__ Whh_r,
    const float* __restrict__ Wih_m, const float* __restrict__ bm_v, const float* __restrict__ Whh_m,
    u8* __restrict__ fwd_all, u8* __restrict__ rev_all, u8* __restrict__ y_all,
    unsigned* __restrict__ flags) {
  __shared__ u8 wslice[32 * 1024];        // 32 KB (fwd/rev use half)
  __shared__ float wih_lds[32 * 66];      // 8448 B
  __shared__ float bias_lds[32];
  __shared__ signed char tok_lds[34 * 256];
  __shared__ u8 hstage[256 * 8];

  const int blk = blockIdx.x;
  const int role = blk < 64 ? 0 : (blk < 128 ? 1 : 2);
  const int HH = (role == 2) ? 1024 : 512;
  const int gbase = role == 0 ? 0 : (role == 1 ? 64 : 128);
  const int gidx  = blk - (role == 0 ? 0 : (role == 1 ? 64 : 128));
  const int gcount = (role == 2) ? 128 : 64;
  const int h0 = gidx * 8;
  const float* Wih  = role == 0 ? Wih_f : role == 1 ? Wih_r : Wih_m;
  const float* bias = role == 0 ? bf_v  : role == 1 ? br_v  : bm_v;
  const float* Whh  = role == 0 ? Whh_f : role == 1 ? Whh_r : Whh_m;
  const int*  tokg  = (role == 2) ? tok_y : tok_x;
  u8* hall = role == 0 ? fwd_all : role == 1 ? rev_all : y_all;

  // ---- stage weight slice (fp8, chunk-XOR swizzle) ----
  {
    const int shift = (HH == 1024) ? 7 : 6;   // log2(HH/8)
    const int K8 = HH >> 3;
    for (int ch = threadIdx.x; ch < 32 * K8; ch += 256) {
      int row = ch >> shift;
      int cc = ch & (K8 - 1);
      int gate = row >> 3, hh2 = row & 7;
      const float* gp = Whh + (size_t)(gate * HH + h0 + hh2) * HH + (cc << 3);
      float4 f0 = *(const float4*)gp;
      float4 f1 = *(const float4*)(gp + 4);
      unsigned w0 = pk2<false>(f0.x, f0.y, 0); w0 = pk2<true>(f0.z, f0.w, w0);
      unsigned w1 = pk2<false>(f1.x, f1.y, 0); w1 = pk2<true>(f1.z, f1.w, w1);
      unsigned off = row * HH + ((cc ^ hh2) << 3);
      *(unsigned*)&wslice[off] = w0;
      *(unsigned*)&wslice[off + 4] = w1;
    }
  }
  for (int i2 = threadIdx.x; i2 < 32 * 66; i2 += 256) {
    int row = i2 / 66, col = i2 - row * 66;
    wih_lds[i2] = Wih[(size_t)((row >> 3) * HH + h0 + (row & 7)) * IND + col];
  }
  if (threadIdx.x < 32)
    bias_lds[threadIdx.x] = bias[(threadIdx.x >> 3) * HH + h0 + (threadIdx.x & 7)];
  for (int i2 = threadIdx.x; i2 < 34 * 256; i2 += 256)
    tok_lds[i2] = (signed char)tokg[i2];
  __syncthreads();

  if (role == 2)
    run_steps<1024>(hall, false, wslice, wih_lds, bias_lds, tok_lds, hstage,
                    flags, gbase, gidx, gcount, h0);
  else
    run_steps<512>(hall, role == 1, wslice, wih_lds, bias_lds, tok_lds, hstage,
                   flags, gbase, gidx, gcount, h0);
}

// ---------------------------------------------------------------------------
// head: lx = x_emb @ W^T, ly = y_emb @ W^T + b, both heads (W rows 0..159).
// 136 blocks x 256 thr; W staged in LDS in 4 K-quarters; A prefetched.
// ---------------------------------------------------------------------------
__global__ __launch_bounds__(256, 1) void head_kernel(
    const u8* __restrict__ fwd_all, const u8* __restrict__ rev_all,
    const u8* __restrict__ y_all, const u8* __restrict__ Wcat,
    const float* __restrict__ b_sub, const float* __restrict__ b_ins,
    float* __restrict__ lx_sub, float* __restrict__ lx_ins,
    float* __restrict__ ly_sub, float* __restrict__ ly_ins) {
  __shared__ u8 wq[160 * 264];   // 42240 B, row pad 264 for bank spread
  const int lane = threadIdx.x & 63, wave = threadIdx.x >> 6;
  const int lo = lane & 15, q = lane >> 4;
  int blk = blockIdx.x;
  bool yside = (blk >= 68);
  int mb = yside ? blk - 68 : blk;
  int ij = mb >> 1;
  int bbase = (mb & 1) * 128;

  f32x4 acc[2][10];
#pragma unroll
  for (int mt = 0; mt < 2; ++mt)
#pragma unroll
    for (int nn = 0; nn < 10; ++nn) acc[mt][nn] = (f32x4){0.f,0.f,0.f,0.f};

  for (int qk = 0; qk < 4; ++qk) {
    for (int c8 = threadIdx.x; c8 < 160 * 32; c8 += 256) {
      int row = c8 >> 5, col = (c8 & 31) << 3;
      *(long*)&wq[row * 264 + col] =
          *(const long*)&Wcat[(size_t)row * 1024 + qk * 256 + col];
    }
    __syncthreads();

    long aA[2][8];
#pragma unroll
    for (int mt = 0; mt < 2; ++mt) {
      int row = bbase + wave * 32 + mt * 16 + lo;
      const u8* ab;
      if (yside)
        ab = y_all + ((size_t)(ij + 1) * 256 + row) * 1024 + qk * 256 + q * 8;
      else if (qk < 2)
        ab = fwd_all + ((size_t)(ij + 1) * 256 + row) * 512 + qk * 256 + q * 8;
      else
        ab = rev_all + ((size_t)(34 - ij) * 256 + row) * 512 + (qk - 2) * 256 + q * 8;
#pragma unroll
      for (int ki = 0; ki < 8; ++ki) aA[mt][ki] = *(const long*)(ab + ki * 32);
    }

#pragma unroll
    for (int ki = 0; ki < 8; ++ki) {
#pragma unroll
      for (int nn = 0; nn < 10; ++nn) {
        long bf = *(const long*)&wq[(nn * 16 + lo) * 264 + ki * 32 + q * 8];
        acc[0][nn] = mfma_fp8(aA[0][ki], bf, acc[0][nn]);
        acc[1][nn] = mfma_fp8(aA[1][ki], bf, acc[1][nn]);
      }
    }
    __syncthreads();
  }

#pragma unroll
  for (int mt = 0; mt < 2; ++mt) {
#pragma unroll
    for (int nn = 0; nn < 10; ++nn) {
      bool is_sub = (nn < 5);
      int n = (is_sub ? nn : nn - 5) * 16 + lo;
      float bias = 0.0f;
      if (yside && n < 65) bias = is_sub ? b_sub[n] : b_ins[n];
      float* dst = yside ? (is_sub ? ly_sub : ly_ins) : (is_sub ? lx_sub : lx_ins);
#pragma unroll
      for (int r = 0; r < 4; ++r) {
        int b = bbase + wave * 32 + mt * 16 + q * 4 + r;
        dst[((size_t)ij * 256 + b) * OP_ + n] = acc[mt][nn][r] + bias;
      }
    }
  }
}

// ---------------------------------------------------------------------------
// pair: per (i,j,b) logsumexp over 65 of lx+ly for both heads.
// 136 blocks (34 i x 4 b-chunks) x 256 thr (64 b x 4 j-lanes); lx in regs.
// ---------------------------------------------------------------------------
__device__ __forceinline__ void lse_regs(const float4* __restrict__ X,
                                         const float* __restrict__ py, int sym,
                                         float& logZ, float& v64, float& vs) {
  const float4* py4 = (const float4*)py;
  float4 Y[17];
#pragma unroll
  for (int q = 0; q < 17; ++q) Y[q] = py4[q];
  float mm = -3.4e38f;
#pragma unroll
  for (int q = 0; q < 17; ++q) {
    float vx[4] = {X[q].x + Y[q].x, X[q].y + Y[q].y, X[q].z + Y[q].z, X[q].w + Y[q].w};
#pragma unroll
    for (int c = 0; c < 4; ++c) {
      int o = q * 4 + c;
      if (o < 65) mm = fmaxf(mm, vx[c]);
    }
  }
  float ss = 0.f, vsl = 0.f, vend = 0.f;
#pragma unroll
  for (int q = 0; q < 17; ++q) {
    float vx[4] = {X[q].x + Y[q].x, X[q].y + Y[q].y, X[q].z + Y[q].z, X[q].w + Y[q].w};
#pragma unroll
    for (int c = 0; c < 4; ++c) {
      int o = q * 4 + c;
      if (o < 65) {
        ss += __expf(vx[c] - mm);
        if (o == 64) vend = vx[c];
        if (o == sym) vsl = vx[c];
      }
    }
  }
  logZ = mm + __logf(ss);
  v64 = vend;
  vs = vsl;
}

__global__ __launch_bounds__(256, 1) void pair_kernel(
    const int* __restrict__ tok_x, const int* __restrict__ tok_y,
    const float* __restrict__ lx_sub, const float* __restrict__ lx_ins,
    const float* __restrict__ ly_sub, const float* __restrict__ ly_ins,
    float* __restrict__ out) {
  const int i = blockIdx.x >> 2;
  const int bc = blockIdx.x & 3;
  const int jq = threadIdx.x >> 6;
  const int bl = threadIdx.x & 63;
  const int b = bc * 64 + bl;
  const size_t CH = (size_t)SX_ * SY_ * B_;

  float4 Xs[17], Xi[17];
  {
    const float4* ps = (const float4*)(lx_sub + ((size_t)i * 256 + b) * OP_);
    const float4* pi = (const float4*)(lx_ins + ((size_t)i * 256 + b) * OP_);
#pragma unroll
    for (int q = 0; q < 17; ++q) { Xs[q] = ps[q]; Xi[q] = pi[q]; }
  }
  int tx = tok_x[i * 256 + b];

  for (int j = jq; j < 34; j += 4) {
    size_t obase = ((size_t)i * SY_ + j) * 256 + b;
    bool dead = (j == SY_ - 1) || (tx < 0);
    if (!dead) {
      int ty = tok_y[j * 256 + b];
      if (ty < 0) dead = true;
    }
    if (dead) {
      out[obase] = BIG_NEG;
      out[CH + obase] = BIG_NEG;
      out[2 * CH + obase] = BIG_NEG;
      out[3 * CH + obase] = BIG_NEG;
      continue;
    }
    int tn = tok_y[(j + 1) * 256 + b];
    bool ins_ok = (tn != 65);
    int sym = (tn >= 0 && tn < 64) ? tn : -1;

    float logZs, v64s, vss;
    lse_regs(Xs, ly_sub + ((size_t)j * 256 + b) * OP_, sym, logZs, v64s, vss);
    float dlt = v64s - logZs;
    float sub_val = (sym >= 0) ? (vss - logZs) : 0.0f;

    float logZi, v64i, vsi;
    lse_regs(Xi, ly_ins + ((size_t)j * 256 + b) * OP_, sym, logZi, v64i, vsi);
    float endv = v64i - logZi;
    float ins_val = (sym >= 0) ? (vsi - logZi) : 0.0f;

    out[obase]          = ins_ok ? ins_val : BIG_NEG;
    out[CH + obase]     = ins_ok ? sub_val : BIG_NEG;
    out[2 * CH + obase] = endv;
    out[3 * CH + obase] = dlt;
  }
}

// ---------------------------------------------------------------------------
// launch
// ---------------------------------------------------------------------------
extern "C" void kernel_launch(void* const* d_in, const int* in_sizes, int n_in,
                              void* d_out, int out_size, void* d_ws, size_t ws_size,
                              hipStream_t stream) {
  const float* sources = (const float*)d_in[0];
  const float* targets = (const float*)d_in[1];
  const float* Wih_f = (const float*)d_in[2];
  const float* Whh_f = (const float*)d_in[3];
  const float* b_f   = (const float*)d_in[4];
  const float* Wih_r = (const float*)d_in[5];
  const float* Whh_r = (const float*)d_in[6];
  const float* b_r   = (const float*)d_in[7];
  const float* Wih_m = (const float*)d_in[8];
  const float* Whh_m = (const float*)d_in[9];
  const float* b_m   = (const float*)d_in[10];
  const float* W_sub = (const float*)d_in[11];
  const float* b_sub = (const float*)d_in[12];
  const float* W_ins = (const float*)d_in[13];
  const float* b_ins = (const float*)d_in[14];
  float* out = (float*)d_out;

  char* w = (char*)d_ws;
  constexpr size_t FLAG_SZ = 1024;                         // 256 unsigned
  constexpr size_t TOK_SZ  = (size_t)SX_ * B_ * 4;
  constexpr size_t WCAT_SZ = (size_t)160 * 1024;           // fp8
  constexpr size_t LX_SZ   = (size_t)SX_ * B_ * OP_ * 4;
  constexpr size_t HF_SZ   = (size_t)35 * B_ * 512;        // fp8
  constexpr size_t HM_SZ   = (size_t)35 * B_ * 1024;       // fp8

  size_t off = 0;
  unsigned* flags = (unsigned*)(w + off); off += FLAG_SZ;
  int*  tok_x   = (int*)(w + off);  off += TOK_SZ;
  int*  tok_y   = (int*)(w + off);  off += TOK_SZ;
  off = (off + 255) & ~(size_t)255;
  u8*   Wcat    = (u8*)(w + off);   off += WCAT_SZ;
  float* lx_sub = (float*)(w + off); off += LX_SZ;
  float* lx_ins = (float*)(w + off); off += LX_SZ;
  float* ly_sub = (float*)(w + off); off += LX_SZ;
  float* ly_ins = (float*)(w + off); off += LX_SZ;
  u8* fwd_all   = (u8*)(w + off);   off += HF_SZ;
  u8* rev_all   = (u8*)(w + off);   off += HF_SZ;
  u8* y_all     = (u8*)(w + off);   off += HM_SZ;
  (void)ws_size; (void)in_sizes; (void)n_in; (void)out_size;

  (void)hipMemsetAsync(flags, 0, FLAG_SZ, stream);

  decode_tokens<<<(2 * SX_ * B_ + 255) / 256, 256, 0, stream>>>(sources, targets, tok_x, tok_y);
  pad_head_w<<<160, 256, 0, stream>>>(W_sub, W_ins, Wcat);

  lstm_persist<<<256, 256, 0, stream>>>(
      tok_x, tok_y,
      Wih_f, b_f, Whh_f,
      Wih_r, b_r, Whh_r,
      Wih_m, b_m, Whh_m,
      fwd_all, rev_all, y_all, flags);

  head_kernel<<<136, 256, 0, stream>>>(fwd_all, rev_all, y_all, Wcat,
                                       b_sub, b_ins, lx_sub, lx_ins, ly_sub, ly_ins);

  pair_kernel<<<136, 256, 0, stream>>>(tok_x, tok_y, lx_sub, lx_ins,
                                       ly_sub, ly_ins, out);
}

// Round 5
// 710.443 us; speedup vs baseline: 2.9149x; 2.9149x over previous
//
#include <hip/hip_runtime.h>

typedef __attribute__((ext_vector_type(4))) float f32x4;
typedef unsigned char u8;
typedef unsigned long long u64t;

#define BIG_NEG -1000000000.0f

static constexpr int B_  = 256;
static constexpr int SX_ = 34;
static constexpr int SY_ = 34;
static constexpr int IND = 66;   // IN_DIM
static constexpr int OP_ = 80;   // padded OUT_DIM (65 -> 80)

__device__ __forceinline__ f32x4 mfma_fp8(long a, long b, f32x4 c) {
  return __builtin_amdgcn_mfma_f32_16x16x32_fp8_fp8(a, b, c, 0, 0, 0);
}
__device__ __forceinline__ float sigm(float x)  { return 1.0f / (1.0f + __expf(-x)); }
__device__ __forceinline__ float tanhx(float x) { return 2.0f * sigm(2.0f * x) - 1.0f; }
template <bool HI>
__device__ __forceinline__ unsigned pk2(float a, float b, unsigned old) {
  return __builtin_amdgcn_cvt_pk_fp8_f32(a, b, (int)old, HI);
}

// ---------------------------------------------------------------------------
// prep kernels
// ---------------------------------------------------------------------------
__global__ void decode_tokens(const float* __restrict__ src,
                              const float* __restrict__ tgt,
                              int* __restrict__ tok_x, int* __restrict__ tok_y) {
  int idx = blockIdx.x * 256 + threadIdx.x;
  const int half = SX_ * B_;
  if (idx >= 2 * half) return;
  const float* base = (idx < half) ? src : tgt;
  int* outp         = (idx < half) ? tok_x : tok_y;
  int k = (idx < half) ? idx : idx - half;
  const float* p = base + (size_t)k * IND;
  int tok = -1;
  for (int v = 0; v < IND; ++v) if (p[v] > 0.5f) tok = v;
  outp[k] = tok;
}

__global__ void conv_fp8(const float* __restrict__ in, u8* __restrict__ out, int n4) {
  int i = blockIdx.x * 256 + threadIdx.x;
  int stride = gridDim.x * 256;
  for (; i < n4; i += stride) {
    float4 f = ((const float4*)in)[i];
    unsigned w = pk2<false>(f.x, f.y, 0);
    w = pk2<true>(f.z, f.w, w);
    ((unsigned*)out)[i] = w;
  }
}

// Wcat: fp8 [160][1024]; rows 0..79 = W_sub (padded), 80..159 = W_ins
__global__ void pad_head_w(const float* __restrict__ Wsub, const float* __restrict__ Wins,
                           u8* __restrict__ Wcat) {
  int widx = blockIdx.x * 256 + threadIdx.x;  // one 4-byte word
  if (widx >= 160 * 256) return;
  int row = widx >> 8;
  int wc  = widx & 255;
  int srow = row < 80 ? row : row - 80;
  const float* W = row < 80 ? Wsub : Wins;
  float f0 = 0.f, f1 = 0.f, f2 = 0.f, f3 = 0.f;
  if (srow < 65) {
    const float* p = W + (size_t)srow * 1024 + wc * 4;
    f0 = p[0]; f1 = p[1]; f2 = p[2]; f3 = p[3];
  }
  unsigned w = pk2<false>(f0, f1, 0);
  w = pk2<true>(f2, f3, w);
  ((unsigned*)Wcat)[widx] = w;
}

// ---------------------------------------------------------------------------
// persistent LSTM: 256 blocks x 256 thr (1/CU), NO fences.
// Block = (batch chunk of 32) x (64 h-units, all 4 gates; N=256 W-rows).
//   b in [0,64)   : fwd  H=512,  b =       c*8  + s  (c chunk, s slice)
//   b in [64,128) : rev  H=512,  b = 64  + c*8  + s
//   b in [128,256): mod  H=1024, b = 128 + c*16 + s
// (ordering puts same-slice blocks on one XCD under blockIdx%8 round-robin —
//  weights stay L2-resident; correctness never depends on the mapping.)
// h exchanged via relaxed agent-scope atomics (LLC-coherent, no wbl2/inv).
// Per-(role,chunk) counter barrier; c-state in registers.
// ---------------------------------------------------------------------------
template <int HH, int NS>
__device__ __forceinline__ void run_lstm(
    const u8* __restrict__ w8, const float* __restrict__ Wih,
    const float* __restrict__ bias, const signed char* __restrict__ tok_lds,
    bool revr, u8* __restrict__ hall, int b0, int h0,
    unsigned* __restrict__ cl, u8* __restrict__ alds) {
  const int tid = threadIdx.x;
  const int lane = tid & 63;
  const int w = tid >> 6;
  const int lo = lane & 15, q = lane >> 4;
  constexpr int AST = HH + 8;          // padded LDS row stride (bytes)
  constexpr int NK = HH / 32;          // 16 or 32 k-iterations
  constexpr int U8C = HH / 8;          // 8B units per row
  constexpr int USH = (HH == 1024) ? 7 : 6;
  const int hu = h0 + w * 16 + lo;     // this lane's h-unit (n dim)

  const u8* brow[4];
  long breg[4][16];                    // resident K (first 512) weights
  float bi[4];
  const float* wr[4];
#pragma unroll
  for (int g = 0; g < 4; ++g) {
    brow[g] = w8 + (size_t)(g * HH + hu) * HH + q * 8;
    bi[g] = bias[g * HH + hu];
    wr[g] = Wih + (size_t)(g * HH + hu) * IND;
#pragma unroll
    for (int kk = 0; kk < 16; ++kk)
      breg[g][kk] = *(const long*)(brow[g] + kk * 32);
  }
  float creg[8] = {0.f, 0.f, 0.f, 0.f, 0.f, 0.f, 0.f, 0.f};

  for (int t = 0; t < 34; ++t) {
    // ---- stage A-tile: h_t[b0..b0+32][0..HH) -> LDS (atomic 8B loads) ----
    const u8* hsrc = hall + (size_t)t * (256 * HH);
#pragma unroll
    for (int ii = 0; ii < (32 * U8C) / 256; ++ii) {
      int idx = tid + ii * 256;
      int m = idx >> USH;
      int u = idx & (U8C - 1);
      u64t v = __hip_atomic_load(
          (const u64t*)(hsrc + (size_t)(b0 + m) * HH + u * 8),
          __ATOMIC_RELAXED, __HIP_MEMORY_SCOPE_AGENT);
      *(u64t*)&alds[m * AST + u * 8] = v;
    }
    __syncthreads();

    f32x4 acc[2][4];
#pragma unroll
    for (int mt = 0; mt < 2; ++mt)
#pragma unroll
      for (int g = 0; g < 4; ++g) acc[mt][g] = (f32x4){0.f, 0.f, 0.f, 0.f};

    const u8* a0p = alds + lo * AST + q * 8;
    const u8* a1p = alds + (16 + lo) * AST + q * 8;
#pragma unroll
    for (int kk = 0; kk < 16; ++kk) {
      long a0 = *(const long*)(a0p + kk * 32);
      long a1 = *(const long*)(a1p + kk * 32);
#pragma unroll
      for (int g = 0; g < 4; ++g) {
        acc[0][g] = mfma_fp8(a0, breg[g][kk], acc[0][g]);
        acc[1][g] = mfma_fp8(a1, breg[g][kk], acc[1][g]);
      }
    }
    if (HH == 1024) {                  // streamed upper-K (L2-resident)
#pragma unroll
      for (int kk = 16; kk < NK; ++kk) {
        long bg[4];
#pragma unroll
        for (int g = 0; g < 4; ++g) bg[g] = *(const long*)(brow[g] + kk * 32);
        long a0 = *(const long*)(a0p + kk * 32);
        long a1 = *(const long*)(a1p + kk * 32);
#pragma unroll
        for (int g = 0; g < 4; ++g) {
          acc[0][g] = mfma_fp8(a0, bg[g], acc[0][g]);
          acc[1][g] = mfma_fp8(a1, bg[g], acc[1][g]);
        }
      }
    }

    // ---- epilogue: lane owns all 4 gates of h-unit `hu` for 8 batch rows ----
    int tpos = revr ? 33 - t : t;
    const signed char* tokp = tok_lds + tpos * 256;
    u8* hdst = hall + (size_t)(t + 1) * (256 * HH);
#pragma unroll
    for (int mt = 0; mt < 2; ++mt) {
#pragma unroll
      for (int r = 0; r < 4; ++r) {
        int m = mt * 16 + q * 4 + r;
        int bb = b0 + m;
        int tk = tokp[bb];
        float g4[4];
#pragma unroll
        for (int g = 0; g < 4; ++g) {
          float v = acc[mt][g][r] + bi[g];
          if (tk >= 0) v += wr[g][tk];
          g4[g] = v;
        }
        float cold = creg[mt * 4 + r];
        float cn = sigm(g4[1]) * cold + sigm(g4[0]) * tanhx(g4[2]);
        float hn = sigm(g4[3]) * tanhx(cn);
        creg[mt * 4 + r] = cn;
        u8 hb = (u8)(pk2<false>(hn, hn, 0) & 0xffu);
        __hip_atomic_store(hdst + (size_t)bb * HH + hu, hb,
                           __ATOMIC_RELAXED, __HIP_MEMORY_SCOPE_AGENT);
      }
    }

    // ---- per-domain barrier: drain stores, count, poll (no fences) ----
    __asm__ volatile("s_waitcnt vmcnt(0)" ::: "memory");
    __syncthreads();
    if (t < 33) {
      if (tid == 0) {
        __hip_atomic_fetch_add(&cl[t], 1u, __ATOMIC_RELAXED,
                               __HIP_MEMORY_SCOPE_AGENT);
        long long tt0 = __builtin_amdgcn_s_memrealtime();
        while (__hip_atomic_load(&cl[t], __ATOMIC_RELAXED,
                                 __HIP_MEMORY_SCOPE_AGENT) < (unsigned)NS) {
          __builtin_amdgcn_s_sleep(1);
          if (__builtin_amdgcn_s_memrealtime() - tt0 > 20000000LL) break;
        }
      }
      __syncthreads();
    }
  }
}

__global__ __launch_bounds__(256, 1) void lstm_persist(
    const int* __restrict__ tok_x, const int* __restrict__ tok_y,
    const float* __restrict__ Wih_f, const float* __restrict__ b_fv, const u8* __restrict__ w8_f,
    const float* __restrict__ Wih_r, const float* __restrict__ b_rv, const u8* __restrict__ w8_r,
    const float* __restrict__ Wih_m, const float* __restrict__ b_mv, const u8* __restrict__ w8_m,
    u8* __restrict__ fwd_all, u8* __restrict__ rev_all, u8* __restrict__ y_all,
    unsigned* __restrict__ cnt) {
  __shared__ u8 alds[32 * 1032];            // 33 KB A-stage (fwd uses 32*520)
  __shared__ signed char tok_lds[34 * 256];

  const int b = blockIdx.x;
  int role, c, s;
  if (b < 64)       { role = 0; c = b >> 3; s = b & 7; }
  else if (b < 128) { int l = b - 64;  role = 1; c = l >> 3; s = l & 7; }
  else              { int l = b - 128; role = 2; c = l >> 4; s = l & 15; }

  const float* Wih  = role == 0 ? Wih_f : role == 1 ? Wih_r : Wih_m;
  const float* bias = role == 0 ? b_fv  : role == 1 ? b_rv  : b_mv;
  const u8*    w8   = role == 0 ? w8_f  : role == 1 ? w8_r  : w8_m;
  u8* hall          = role == 0 ? fwd_all : role == 1 ? rev_all : y_all;
  const int* tokg   = (role == 2) ? tok_y : tok_x;

  for (int i = threadIdx.x; i < 34 * 256; i += 256)
    tok_lds[i] = (signed char)tokg[i];
  __syncthreads();

  unsigned* cl = cnt + (role * 8 + c) * 34;
  const int b0 = c * 32;
  const int h0 = s * 64;
  if (role == 2)
    run_lstm<1024, 16>(w8, Wih, bias, tok_lds, false, hall, b0, h0, cl, alds);
  else
    run_lstm<512, 8>(w8, Wih, bias, tok_lds, role == 1, hall, b0, h0, cl, alds);
}

// ---------------------------------------------------------------------------
// head: lx = x_emb @ W^T, ly = y_emb @ W^T + b, both heads (W rows 0..159).
// 136 blocks x 256 thr; W staged in LDS in 4 K-quarters; A prefetched.
// ---------------------------------------------------------------------------
__global__ __launch_bounds__(256, 1) void head_kernel(
    const u8* __restrict__ fwd_all, const u8* __restrict__ rev_all,
    const u8* __restrict__ y_all, const u8* __restrict__ Wcat,
    const float* __restrict__ b_sub, const float* __restrict__ b_ins,
    float* __restrict__ lx_sub, float* __restrict__ lx_ins,
    float* __restrict__ ly_sub, float* __restrict__ ly_ins) {
  __shared__ u8 wq[160 * 264];   // 42240 B, row pad 264 for bank spread
  const int lane = threadIdx.x & 63, wave = threadIdx.x >> 6;
  const int lo = lane & 15, q = lane >> 4;
  int blk = blockIdx.x;
  bool yside = (blk >= 68);
  int mb = yside ? blk - 68 : blk;
  int ij = mb >> 1;
  int bbase = (mb & 1) * 128;

  f32x4 acc[2][10];
#pragma unroll
  for (int mt = 0; mt < 2; ++mt)
#pragma unroll
    for (int nn = 0; nn < 10; ++nn) acc[mt][nn] = (f32x4){0.f,0.f,0.f,0.f};

  for (int qk = 0; qk < 4; ++qk) {
    for (int c8 = threadIdx.x; c8 < 160 * 32; c8 += 256) {
      int row = c8 >> 5, col = (c8 & 31) << 3;
      *(long*)&wq[row * 264 + col] =
          *(const long*)&Wcat[(size_t)row * 1024 + qk * 256 + col];
    }
    __syncthreads();

    long aA[2][8];
#pragma unroll
    for (int mt = 0; mt < 2; ++mt) {
      int row = bbase + wave * 32 + mt * 16 + lo;
      const u8* ab;
      if (yside)
        ab = y_all + ((size_t)(ij + 1) * 256 + row) * 1024 + qk * 256 + q * 8;
      else if (qk < 2)
        ab = fwd_all + ((size_t)(ij + 1) * 256 + row) * 512 + qk * 256 + q * 8;
      else
        ab = rev_all + ((size_t)(34 - ij) * 256 + row) * 512 + (qk - 2) * 256 + q * 8;
#pragma unroll
      for (int ki = 0; ki < 8; ++ki) aA[mt][ki] = *(const long*)(ab + ki * 32);
    }

#pragma unroll
    for (int ki = 0; ki < 8; ++ki) {
#pragma unroll
      for (int nn = 0; nn < 10; ++nn) {
        long bf = *(const long*)&wq[(nn * 16 + lo) * 264 + ki * 32 + q * 8];
        acc[0][nn] = mfma_fp8(aA[0][ki], bf, acc[0][nn]);
        acc[1][nn] = mfma_fp8(aA[1][ki], bf, acc[1][nn]);
      }
    }
    __syncthreads();
  }

#pragma unroll
  for (int mt = 0; mt < 2; ++mt) {
#pragma unroll
    for (int nn = 0; nn < 10; ++nn) {
      bool is_sub = (nn < 5);
      int n = (is_sub ? nn : nn - 5) * 16 + lo;
      float bias = 0.0f;
      if (yside && n < 65) bias = is_sub ? b_sub[n] : b_ins[n];
      float* dst = yside ? (is_sub ? ly_sub : ly_ins) : (is_sub ? lx_sub : lx_ins);
#pragma unroll
      for (int r = 0; r < 4; ++r) {
        int b = bbase + wave * 32 + mt * 16 + q * 4 + r;
        dst[((size_t)ij * 256 + b) * OP_ + n] = acc[mt][nn][r] + bias;
      }
    }
  }
}

// ---------------------------------------------------------------------------
// pair: per (i,j,b) logsumexp over 65 of lx+ly for both heads.
// 136 blocks (34 i x 4 b-chunks) x 256 thr (64 b x 4 j-lanes); lx in regs.
// ---------------------------------------------------------------------------
__device__ __forceinline__ void lse_regs(const float4* __restrict__ X,
                                         const float* __restrict__ py, int sym,
                                         float& logZ, float& v64, float& vs) {
  const float4* py4 = (const float4*)py;
  float4 Y[17];
#pragma unroll
  for (int q = 0; q < 17; ++q) Y[q] = py4[q];
  float mm = -3.4e38f;
#pragma unroll
  for (int q = 0; q < 17; ++q) {
    float vx[4] = {X[q].x + Y[q].x, X[q].y + Y[q].y, X[q].z + Y[q].z, X[q].w + Y[q].w};
#pragma unroll
    for (int c = 0; c < 4; ++c) {
      int o = q * 4 + c;
      if (o < 65) mm = fmaxf(mm, vx[c]);
    }
  }
  float ss = 0.f, vsl = 0.f, vend = 0.f;
#pragma unroll
  for (int q = 0; q < 17; ++q) {
    float vx[4] = {X[q].x + Y[q].x, X[q].y + Y[q].y, X[q].z + Y[q].z, X[q].w + Y[q].w};
#pragma unroll
    for (int c = 0; c < 4; ++c) {
      int o = q * 4 + c;
      if (o < 65) {
        ss += __expf(vx[c] - mm);
        if (o == 64) vend = vx[c];
        if (o == sym) vsl = vx[c];
      }
    }
  }
  logZ = mm + __logf(ss);
  v64 = vend;
  vs = vsl;
}

__global__ __launch_bounds__(256, 1) void pair_kernel(
    const int* __restrict__ tok_x, const int* __restrict__ tok_y,
    const float* __restrict__ lx_sub, const float* __restrict__ lx_ins,
    const float* __restrict__ ly_sub, const float* __restrict__ ly_ins,
    float* __restrict__ out) {
  const int i = blockIdx.x >> 2;
  const int bc = blockIdx.x & 3;
  const int jq = threadIdx.x >> 6;
  const int bl = threadIdx.x & 63;
  const int b = bc * 64 + bl;
  const size_t CH = (size_t)SX_ * SY_ * B_;

  float4 Xs[17], Xi[17];
  {
    const float4* ps = (const float4*)(lx_sub + ((size_t)i * 256 + b) * OP_);
    const float4* pi = (const float4*)(lx_ins + ((size_t)i * 256 + b) * OP_);
#pragma unroll
    for (int q = 0; q < 17; ++q) { Xs[q] = ps[q]; Xi[q] = pi[q]; }
  }
  int tx = tok_x[i * 256 + b];

  for (int j = jq; j < 34; j += 4) {
    size_t obase = ((size_t)i * SY_ + j) * 256 + b;
    bool dead = (j == SY_ - 1) || (tx < 0);
    if (!dead) {
      int ty = tok_y[j * 256 + b];
      if (ty < 0) dead = true;
    }
    if (dead) {
      out[obase] = BIG_NEG;
      out[CH + obase] = BIG_NEG;
      out[2 * CH + obase] = BIG_NEG;
      out[3 * CH + obase] = BIG_NEG;
      continue;
    }
    int tn = tok_y[(j + 1) * 256 + b];
    bool ins_ok = (tn != 65);
    int sym = (tn >= 0 && tn < 64) ? tn : -1;

    float logZs, v64s, vss;
    lse_regs(Xs, ly_sub + ((size_t)j * 256 + b) * OP_, sym, logZs, v64s, vss);
    float dlt = v64s - logZs;
    float sub_val = (sym >= 0) ? (vss - logZs) : 0.0f;

    float logZi, v64i, vsi;
    lse_regs(Xi, ly_ins + ((size_t)j * 256 + b) * OP_, sym, logZi, v64i, vsi);
    float endv = v64i - logZi;
    float ins_val = (sym >= 0) ? (vsi - logZi) : 0.0f;

    out[obase]          = ins_ok ? ins_val : BIG_NEG;
    out[CH + obase]     = ins_ok ? sub_val : BIG_NEG;
    out[2 * CH + obase] = endv;
    out[3 * CH + obase] = dlt;
  }
}

// ---------------------------------------------------------------------------
// launch
// ---------------------------------------------------------------------------
extern "C" void kernel_launch(void* const* d_in, const int* in_sizes, int n_in,
                              void* d_out, int out_size, void* d_ws, size_t ws_size,
                              hipStream_t stream) {
  const float* sources = (const float*)d_in[0];
  const float* targets = (const float*)d_in[1];
  const float* Wih_f = (const float*)d_in[2];
  const float* Whh_f = (const float*)d_in[3];
  const float* b_f   = (const float*)d_in[4];
  const float* Wih_r = (const float*)d_in[5];
  const float* Whh_r = (const float*)d_in[6];
  const float* b_r   = (const float*)d_in[7];
  const float* Wih_m = (const float*)d_in[8];
  const float* Whh_m = (const float*)d_in[9];
  const float* b_m   = (const float*)d_in[10];
  const float* W_sub = (const float*)d_in[11];
  const float* b_sub = (const float*)d_in[12];
  const float* W_ins = (const float*)d_in[13];
  const float* b_ins = (const float*)d_in[14];
  float* out = (float*)d_out;

  char* w = (char*)d_ws;
  constexpr size_t CNT_SZ  = 4096;                          // 24 domains x 34
  constexpr size_t TOK_SZ  = (size_t)SX_ * B_ * 4;
  constexpr size_t WCAT_SZ = (size_t)160 * 1024;            // head W fp8
  constexpr size_t W8F_SZ  = (size_t)2048 * 512;            // fwd Whh fp8
  constexpr size_t W8M_SZ  = (size_t)4096 * 1024;           // mod Whh fp8
  constexpr size_t LX_SZ   = (size_t)SX_ * B_ * OP_ * 4;
  constexpr size_t HF_SZ   = (size_t)35 * B_ * 512;         // h slabs fp8
  constexpr size_t HM_SZ   = (size_t)35 * B_ * 1024;

  size_t off = 0;
  unsigned* cnt = (unsigned*)(w + off); off += CNT_SZ;
  int*  tok_x   = (int*)(w + off);  off += TOK_SZ;
  int*  tok_y   = (int*)(w + off);  off += TOK_SZ;
  off = (off + 255) & ~(size_t)255;
  u8*   Wcat    = (u8*)(w + off);   off += WCAT_SZ;
  u8*   w8_f    = (u8*)(w + off);   off += W8F_SZ;
  u8*   w8_r    = (u8*)(w + off);   off += W8F_SZ;
  u8*   w8_m    = (u8*)(w + off);   off += W8M_SZ;
  float* lx_sub = (float*)(w + off); off += LX_SZ;
  float* lx_ins = (float*)(w + off); off += LX_SZ;
  float* ly_sub = (float*)(w + off); off += LX_SZ;
  float* ly_ins = (float*)(w + off); off += LX_SZ;
  u8* fwd_all   = (u8*)(w + off);   off += HF_SZ;
  u8* rev_all   = (u8*)(w + off);   off += HF_SZ;
  u8* y_all     = (u8*)(w + off);   off += HM_SZ;
  (void)ws_size; (void)in_sizes; (void)n_in; (void)out_size;

  // zero: barrier counters + t=0 h slabs
  (void)hipMemsetAsync(cnt, 0, CNT_SZ, stream);
  (void)hipMemsetAsync(fwd_all, 0, (size_t)B_ * 512, stream);
  (void)hipMemsetAsync(rev_all, 0, (size_t)B_ * 512, stream);
  (void)hipMemsetAsync(y_all,   0, (size_t)B_ * 1024, stream);

  decode_tokens<<<(2 * SX_ * B_ + 255) / 256, 256, 0, stream>>>(sources, targets, tok_x, tok_y);
  pad_head_w<<<160, 256, 0, stream>>>(W_sub, W_ins, Wcat);
  conv_fp8<<<1024, 256, 0, stream>>>(Whh_f, w8_f, 2048 * 512 / 4);
  conv_fp8<<<1024, 256, 0, stream>>>(Whh_r, w8_r, 2048 * 512 / 4);
  conv_fp8<<<2048, 256, 0, stream>>>(Whh_m, w8_m, 4096 * 1024 / 4);

  lstm_persist<<<256, 256, 0, stream>>>(
      tok_x, tok_y,
      Wih_f, b_f, w8_f,
      Wih_r, b_r, w8_r,
      Wih_m, b_m, w8_m,
      fwd_all, rev_all, y_all, cnt);

  head_kernel<<<136, 256, 0, stream>>>(fwd_all, rev_all, y_all, Wcat,
                                       b_sub, b_ins, lx_sub, lx_ins, ly_sub, ly_ins);

  pair_kernel<<<136, 256, 0, stream>>>(tok_x, tok_y, lx_sub, lx_ins,
                                       ly_sub, ly_ins, out);
}

// Round 6
// 476.589 us; speedup vs baseline: 4.3452x; 1.4907x over previous
//
#include <hip/hip_runtime.h>

typedef __attribute__((ext_vector_type(4))) float f32x4;
typedef unsigned char u8;
typedef unsigned long long u64t;

#define BIG_NEG -1000000000.0f

static constexpr int B_  = 256;
static constexpr int SX_ = 34;
static constexpr int SY_ = 34;
static constexpr int IND = 66;   // IN_DIM
static constexpr int OP_ = 80;   // padded OUT_DIM (65 -> 80)

__device__ __forceinline__ f32x4 mfma_fp8(long a, long b, f32x4 c) {
  return __builtin_amdgcn_mfma_f32_16x16x32_fp8_fp8(a, b, c, 0, 0, 0);
}
__device__ __forceinline__ float sigm(float x)  { return 1.0f / (1.0f + __expf(-x)); }
__device__ __forceinline__ float tanhx(float x) { return 2.0f * sigm(2.0f * x) - 1.0f; }
template <bool HI>
__device__ __forceinline__ unsigned pk2(float a, float b, unsigned old) {
  return __builtin_amdgcn_cvt_pk_fp8_f32(a, b, (int)old, HI);
}

// ---------------------------------------------------------------------------
// prep kernels
// ---------------------------------------------------------------------------
__global__ void decode_tokens(const float* __restrict__ src,
                              const float* __restrict__ tgt,
                              int* __restrict__ tok_x, int* __restrict__ tok_y) {
  int idx = blockIdx.x * 256 + threadIdx.x;
  const int half = SX_ * B_;
  if (idx >= 2 * half) return;
  const float* base = (idx < half) ? src : tgt;
  int* outp         = (idx < half) ? tok_x : tok_y;
  int k = (idx < half) ? idx : idx - half;
  const float* p = base + (size_t)k * IND;
  int tok = -1;
  for (int v = 0; v < IND; ++v) if (p[v] > 0.5f) tok = v;
  outp[k] = tok;
}

__global__ void conv_fp8(const float* __restrict__ in, u8* __restrict__ out, int n4) {
  int i = blockIdx.x * 256 + threadIdx.x;
  int stride = gridDim.x * 256;
  for (; i < n4; i += stride) {
    float4 f = ((const float4*)in)[i];
    unsigned w = pk2<false>(f.x, f.y, 0);
    w = pk2<true>(f.z, f.w, w);
    ((unsigned*)out)[i] = w;
  }
}

// E[v][n] = (v<66 ? Wih[n][v] : 0) + bias[n], v in [0,67), n in [0,4H)
__global__ void build_E(const float* __restrict__ Wih, const float* __restrict__ bias,
                        float* __restrict__ E, int sh) {
  int idx = blockIdx.x * 256 + threadIdx.x;
  int H4 = 1 << sh;
  if (idx >= 67 * H4) return;
  int v = idx >> sh;
  int n = idx & (H4 - 1);
  float val = bias[n];
  if (v < 66) val += Wih[(size_t)n * IND + v];
  E[idx] = val;
}

// Wcat: fp8 [160][1024]; rows 0..79 = W_sub (padded), 80..159 = W_ins
__global__ void pad_head_w(const float* __restrict__ Wsub, const float* __restrict__ Wins,
                           u8* __restrict__ Wcat) {
  int widx = blockIdx.x * 256 + threadIdx.x;  // one 4-byte word
  if (widx >= 160 * 256) return;
  int row = widx >> 8;
  int wc  = widx & 255;
  int srow = row < 80 ? row : row - 80;
  const float* W = row < 80 ? Wsub : Wins;
  float f0 = 0.f, f1 = 0.f, f2 = 0.f, f3 = 0.f;
  if (srow < 65) {
    const float* p = W + (size_t)srow * 1024 + wc * 4;
    f0 = p[0]; f1 = p[1]; f2 = p[2]; f3 = p[3];
  }
  unsigned w = pk2<false>(f0, f1, 0);
  w = pk2<true>(f2, f3, w);
  ((unsigned*)Wcat)[widx] = w;
}

// ---------------------------------------------------------------------------
// persistent LSTM: 256 blocks x 256 thr (1/CU), NO fences.
// Block = (batch chunk of 32) x (64 h-units, all 4 gates; N=256 W-rows).
// h exchanged via relaxed agent-scope atomics (LLC-coherent, no wbl2/inv):
//  - A-stage: all loads batched into regs, then LDS (one latency epoch)
//  - h store: LDS transpose -> one coalesced 8B store/thread
//  - gate constants via E-table gather (coalesced 64B segments)
// Per-(role,chunk) counter barrier; c-state in registers.
// ---------------------------------------------------------------------------
template <int HH, int NS>
__device__ __forceinline__ void run_lstm(
    const u8* __restrict__ w8, const float* __restrict__ E,
    bool revr, u8* __restrict__ hall, int b0, int h0,
    unsigned* __restrict__ cl, u8* __restrict__ alds,
    u8* __restrict__ hT, const u8* __restrict__ tok_small) {
  const int tid = threadIdx.x;
  const int lane = tid & 63, w = tid >> 6;
  const int lo = lane & 15, q = lane >> 4;
  constexpr int AST = HH + 8;          // padded LDS row stride (bytes)
  constexpr int U8C = HH / 8;
  constexpr int USH = (HH == 1024) ? 7 : 6;
  constexpr int NI  = (32 * U8C) / 256;   // 8 (fwd/rev) or 16 (mod)
  constexpr int NK  = HH / 32;
  const int hu = h0 + w * 16 + lo;     // this lane's h-unit

  const u8* brow[4];
  long breg[4][16];                    // resident K (first 512) weights
#pragma unroll
  for (int g = 0; g < 4; ++g) {
    brow[g] = w8 + (size_t)(g * HH + hu) * HH + q * 8;
#pragma unroll
    for (int kk = 0; kk < 16; ++kk)
      breg[g][kk] = *(const long*)(brow[g] + kk * 32);
  }
  float creg[8] = {0.f, 0.f, 0.f, 0.f, 0.f, 0.f, 0.f, 0.f};

  for (int t = 0; t < 34; ++t) {
    // ---- stage A-tile: batched atomic loads -> regs -> LDS ----
    const u8* hsrc = hall + (size_t)t * (256 * HH);
    u64t tmp[NI];
#pragma unroll
    for (int ii = 0; ii < NI; ++ii) {
      int idx = tid + ii * 256;
      tmp[ii] = __hip_atomic_load(
          (const u64t*)(hsrc + (size_t)(b0 + (idx >> USH)) * HH + (idx & (U8C - 1)) * 8),
          __ATOMIC_RELAXED, __HIP_MEMORY_SCOPE_AGENT);
    }
#pragma unroll
    for (int ii = 0; ii < NI; ++ii) {
      int idx = tid + ii * 256;
      *(u64t*)&alds[(idx >> USH) * AST + (idx & (U8C - 1)) * 8] = tmp[ii];
    }
    __syncthreads();

    f32x4 acc[2][4];
#pragma unroll
    for (int mt = 0; mt < 2; ++mt)
#pragma unroll
      for (int g = 0; g < 4; ++g) acc[mt][g] = (f32x4){0.f, 0.f, 0.f, 0.f};

    const u8* a0p = alds + lo * AST + q * 8;
    const u8* a1p = alds + (16 + lo) * AST + q * 8;
#pragma unroll
    for (int kk = 0; kk < 16; ++kk) {
      long a0 = *(const long*)(a0p + kk * 32);
      long a1 = *(const long*)(a1p + kk * 32);
#pragma unroll
      for (int g = 0; g < 4; ++g) {
        acc[0][g] = mfma_fp8(a0, breg[g][kk], acc[0][g]);
        acc[1][g] = mfma_fp8(a1, breg[g][kk], acc[1][g]);
      }
    }
    if (HH == 1024) {                  // streamed upper-K (L2-resident)
#pragma unroll
      for (int kk = 16; kk < NK; ++kk) {
        long bg[4];
#pragma unroll
        for (int g = 0; g < 4; ++g) bg[g] = *(const long*)(brow[g] + kk * 32);
        long a0 = *(const long*)(a0p + kk * 32);
        long a1 = *(const long*)(a1p + kk * 32);
#pragma unroll
        for (int g = 0; g < 4; ++g) {
          acc[0][g] = mfma_fp8(a0, bg[g], acc[0][g]);
          acc[1][g] = mfma_fp8(a1, bg[g], acc[1][g]);
        }
      }
    }

    // ---- epilogue: E-gather + gate math; pack fp8 into hT (LDS) ----
    int tpos = revr ? 33 - t : t;
    const u8* tkp = tok_small + tpos * 32;
#pragma unroll
    for (int mt = 0; mt < 2; ++mt) {
      float hv[4];
#pragma unroll
      for (int r = 0; r < 4; ++r) {
        int m = mt * 16 + q * 4 + r;
        int v = tkp[m];
        const float* e = E + (size_t)v * (4 * HH) + hu;
        float g4[4];
#pragma unroll
        for (int g = 0; g < 4; ++g) g4[g] = acc[mt][g][r] + e[g * HH];
        float cold = creg[mt * 4 + r];
        float cn = sigm(g4[1]) * cold + sigm(g4[0]) * tanhx(g4[2]);
        hv[r] = sigm(g4[3]) * tanhx(cn);
        creg[mt * 4 + r] = cn;
      }
      unsigned pw = pk2<false>(hv[0], hv[1], 0);
      pw = pk2<true>(hv[2], hv[3], pw);
      *(unsigned*)&hT[(w * 16 + lo) * 36 + mt * 16 + q * 4] = pw;
    }
    __syncthreads();

    // ---- coalesced 8B agent store: thread -> (row m, 8-col chunk cc) ----
    {
      int m = tid >> 3, cc = tid & 7;
      u64t val = 0;
#pragma unroll
      for (int k = 0; k < 8; ++k)
        val |= (u64t)hT[(cc * 8 + k) * 36 + m] << (8 * k);
      u8* hdst = hall + (size_t)(t + 1) * (256 * HH);
      __hip_atomic_store((u64t*)(hdst + (size_t)(b0 + m) * HH + h0 + cc * 8), val,
                         __ATOMIC_RELAXED, __HIP_MEMORY_SCOPE_AGENT);
    }

    // ---- per-domain barrier: drain stores, count, poll ----
    if (t < 33) {
      __asm__ volatile("s_waitcnt vmcnt(0)" ::: "memory");
      __syncthreads();
      if (tid == 0) {
        __hip_atomic_fetch_add(&cl[t], 1u, __ATOMIC_RELAXED,
                               __HIP_MEMORY_SCOPE_AGENT);
        long long tt0 = __builtin_amdgcn_s_memrealtime();
        while (__hip_atomic_load(&cl[t], __ATOMIC_RELAXED,
                                 __HIP_MEMORY_SCOPE_AGENT) < (unsigned)NS) {
          __builtin_amdgcn_s_sleep(1);
          if (__builtin_amdgcn_s_memrealtime() - tt0 > 20000000LL) break;
        }
      }
      __syncthreads();
    }
  }
}

__global__ __launch_bounds__(256, 1) void lstm_persist(
    const int* __restrict__ tok_x, const int* __restrict__ tok_y,
    const float* __restrict__ E_f, const u8* __restrict__ w8_f,
    const float* __restrict__ E_r, const u8* __restrict__ w8_r,
    const float* __restrict__ E_m, const u8* __restrict__ w8_m,
    u8* __restrict__ fwd_all, u8* __restrict__ rev_all, u8* __restrict__ y_all,
    unsigned* __restrict__ cnt) {
  __shared__ u8 alds[32 * 1032];       // 33 KB A-stage (fwd/rev use 32*520)
  __shared__ u8 hT[64 * 36];           // store-transpose buffer
  __shared__ u8 tok_small[34 * 32];    // this block's tokens (66 = none)

  const int b = blockIdx.x;
  int role, c, s;
  if (b < 64)       { role = 0; c = b >> 3; s = b & 7; }
  else if (b < 128) { int l = b - 64;  role = 1; c = l >> 3; s = l & 7; }
  else              { int l = b - 128; role = 2; c = l >> 4; s = l & 15; }

  const float* E  = role == 0 ? E_f  : role == 1 ? E_r  : E_m;
  const u8*    w8 = role == 0 ? w8_f : role == 1 ? w8_r : w8_m;
  u8* hall        = role == 0 ? fwd_all : role == 1 ? rev_all : y_all;
  const int* tokg = (role == 2) ? tok_y : tok_x;
  const int b0 = c * 32;
  const int h0 = s * 64;

  for (int i = threadIdx.x; i < 34 * 32; i += 256) {
    int t2 = i >> 5, m = i & 31;
    int tk = tokg[t2 * 256 + b0 + m];
    tok_small[i] = (u8)(tk < 0 ? 66 : tk);
  }
  __syncthreads();

  unsigned* cl = cnt + (role * 8 + c) * 34;
  if (role == 2)
    run_lstm<1024, 16>(w8, E, false, hall, b0, h0, cl, alds, hT, tok_small);
  else
    run_lstm<512, 8>(w8, E, role == 1, hall, b0, h0, cl, alds, hT, tok_small);
}

// ---------------------------------------------------------------------------
// head: lx = x_emb @ W^T, ly = y_emb @ W^T + b, both heads (W rows 0..159).
// 136 blocks x 256 thr; W staged in LDS in 4 K-quarters; A prefetched.
// ---------------------------------------------------------------------------
__global__ __launch_bounds__(256, 1) void head_kernel(
    const u8* __restrict__ fwd_all, const u8* __restrict__ rev_all,
    const u8* __restrict__ y_all, const u8* __restrict__ Wcat,
    const float* __restrict__ b_sub, const float* __restrict__ b_ins,
    float* __restrict__ lx_sub, float* __restrict__ lx_ins,
    float* __restrict__ ly_sub, float* __restrict__ ly_ins) {
  __shared__ u8 wq[160 * 264];   // 42240 B, row pad 264 for bank spread
  const int lane = threadIdx.x & 63, wave = threadIdx.x >> 6;
  const int lo = lane & 15, q = lane >> 4;
  int blk = blockIdx.x;
  bool yside = (blk >= 68);
  int mb = yside ? blk - 68 : blk;
  int ij = mb >> 1;
  int bbase = (mb & 1) * 128;

  f32x4 acc[2][10];
#pragma unroll
  for (int mt = 0; mt < 2; ++mt)
#pragma unroll
    for (int nn = 0; nn < 10; ++nn) acc[mt][nn] = (f32x4){0.f,0.f,0.f,0.f};

  for (int qk = 0; qk < 4; ++qk) {
    for (int c8 = threadIdx.x; c8 < 160 * 32; c8 += 256) {
      int row = c8 >> 5, col = (c8 & 31) << 3;
      *(long*)&wq[row * 264 + col] =
          *(const long*)&Wcat[(size_t)row * 1024 + qk * 256 + col];
    }
    __syncthreads();

    long aA[2][8];
#pragma unroll
    for (int mt = 0; mt < 2; ++mt) {
      int row = bbase + wave * 32 + mt * 16 + lo;
      const u8* ab;
      if (yside)
        ab = y_all + ((size_t)(ij + 1) * 256 + row) * 1024 + qk * 256 + q * 8;
      else if (qk < 2)
        ab = fwd_all + ((size_t)(ij + 1) * 256 + row) * 512 + qk * 256 + q * 8;
      else
        ab = rev_all + ((size_t)(34 - ij) * 256 + row) * 512 + (qk - 2) * 256 + q * 8;
#pragma unroll
      for (int ki = 0; ki < 8; ++ki) aA[mt][ki] = *(const long*)(ab + ki * 32);
    }

#pragma unroll
    for (int ki = 0; ki < 8; ++ki) {
#pragma unroll
      for (int nn = 0; nn < 10; ++nn) {
        long bf = *(const long*)&wq[(nn * 16 + lo) * 264 + ki * 32 + q * 8];
        acc[0][nn] = mfma_fp8(aA[0][ki], bf, acc[0][nn]);
        acc[1][nn] = mfma_fp8(aA[1][ki], bf, acc[1][nn]);
      }
    }
    __syncthreads();
  }

#pragma unroll
  for (int mt = 0; mt < 2; ++mt) {
#pragma unroll
    for (int nn = 0; nn < 10; ++nn) {
      bool is_sub = (nn < 5);
      int n = (is_sub ? nn : nn - 5) * 16 + lo;
      float bias = 0.0f;
      if (yside && n < 65) bias = is_sub ? b_sub[n] : b_ins[n];
      float* dst = yside ? (is_sub ? ly_sub : ly_ins) : (is_sub ? lx_sub : lx_ins);
#pragma unroll
      for (int r = 0; r < 4; ++r) {
        int b = bbase + wave * 32 + mt * 16 + q * 4 + r;
        dst[((size_t)ij * 256 + b) * OP_ + n] = acc[mt][nn][r] + bias;
      }
    }
  }
}

// ---------------------------------------------------------------------------
// pair: per (i,j,b) logsumexp over 65 of lx+ly for both heads.
// 136 blocks (34 i x 4 b-chunks) x 256 thr (64 b x 4 j-lanes); lx in regs.
// ---------------------------------------------------------------------------
__device__ __forceinline__ void lse_regs(const float4* __restrict__ X,
                                         const float* __restrict__ py, int sym,
                                         float& logZ, float& v64, float& vs) {
  const float4* py4 = (const float4*)py;
  float4 Y[17];
#pragma unroll
  for (int q = 0; q < 17; ++q) Y[q] = py4[q];
  float mm = -3.4e38f;
#pragma unroll
  for (int q = 0; q < 17; ++q) {
    float vx[4] = {X[q].x + Y[q].x, X[q].y + Y[q].y, X[q].z + Y[q].z, X[q].w + Y[q].w};
#pragma unroll
    for (int c = 0; c < 4; ++c) {
      int o = q * 4 + c;
      if (o < 65) mm = fmaxf(mm, vx[c]);
    }
  }
  float ss = 0.f, vsl = 0.f, vend = 0.f;
#pragma unroll
  for (int q = 0; q < 17; ++q) {
    float vx[4] = {X[q].x + Y[q].x, X[q].y + Y[q].y, X[q].z + Y[q].z, X[q].w + Y[q].w};
#pragma unroll
    for (int c = 0; c < 4; ++c) {
      int o = q * 4 + c;
      if (o < 65) {
        ss += __expf(vx[c] - mm);
        if (o == 64) vend = vx[c];
        if (o == sym) vsl = vx[c];
      }
    }
  }
  logZ = mm + __logf(ss);
  v64 = vend;
  vs = vsl;
}

__global__ __launch_bounds__(256, 1) void pair_kernel(
    const int* __restrict__ tok_x, const int* __restrict__ tok_y,
    const float* __restrict__ lx_sub, const float* __restrict__ lx_ins,
    const float* __restrict__ ly_sub, const float* __restrict__ ly_ins,
    float* __restrict__ out) {
  const int i = blockIdx.x >> 2;
  const int bc = blockIdx.x & 3;
  const int jq = threadIdx.x >> 6;
  const int bl = threadIdx.x & 63;
  const int b = bc * 64 + bl;
  const size_t CH = (size_t)SX_ * SY_ * B_;

  float4 Xs[17], Xi[17];
  {
    const float4* ps = (const float4*)(lx_sub + ((size_t)i * 256 + b) * OP_);
    const float4* pi = (const float4*)(lx_ins + ((size_t)i * 256 + b) * OP_);
#pragma unroll
    for (int q = 0; q < 17; ++q) { Xs[q] = ps[q]; Xi[q] = pi[q]; }
  }
  int tx = tok_x[i * 256 + b];

  for (int j = jq; j < 34; j += 4) {
    size_t obase = ((size_t)i * SY_ + j) * 256 + b;
    bool dead = (j == SY_ - 1) || (tx < 0);
    if (!dead) {
      int ty = tok_y[j * 256 + b];
      if (ty < 0) dead = true;
    }
    if (dead) {
      out[obase] = BIG_NEG;
      out[CH + obase] = BIG_NEG;
      out[2 * CH + obase] = BIG_NEG;
      out[3 * CH + obase] = BIG_NEG;
      continue;
    }
    int tn = tok_y[(j + 1) * 256 + b];
    bool ins_ok = (tn != 65);
    int sym = (tn >= 0 && tn < 64) ? tn : -1;

    float logZs, v64s, vss;
    lse_regs(Xs, ly_sub + ((size_t)j * 256 + b) * OP_, sym, logZs, v64s, vss);
    float dlt = v64s - logZs;
    float sub_val = (sym >= 0) ? (vss - logZs) : 0.0f;

    float logZi, v64i, vsi;
    lse_regs(Xi, ly_ins + ((size_t)j * 256 + b) * OP_, sym, logZi, v64i, vsi);
    float endv = v64i - logZi;
    float ins_val = (sym >= 0) ? (vsi - logZi) : 0.0f;

    out[obase]          = ins_ok ? ins_val : BIG_NEG;
    out[CH + obase]     = ins_ok ? sub_val : BIG_NEG;
    out[2 * CH + obase] = endv;
    out[3 * CH + obase] = dlt;
  }
}

// ---------------------------------------------------------------------------
// launch
// ---------------------------------------------------------------------------
extern "C" void kernel_launch(void* const* d_in, const int* in_sizes, int n_in,
                              void* d_out, int out_size, void* d_ws, size_t ws_size,
                              hipStream_t stream) {
  const float* sources = (const float*)d_in[0];
  const float* targets = (const float*)d_in[1];
  const float* Wih_f = (const float*)d_in[2];
  const float* Whh_f = (const float*)d_in[3];
  const float* b_f   = (const float*)d_in[4];
  const float* Wih_r = (const float*)d_in[5];
  const float* Whh_r = (const float*)d_in[6];
  const float* b_r   = (const float*)d_in[7];
  const float* Wih_m = (const float*)d_in[8];
  const float* Whh_m = (const float*)d_in[9];
  const float* b_m   = (const float*)d_in[10];
  const float* W_sub = (const float*)d_in[11];
  const float* b_sub = (const float*)d_in[12];
  const float* W_ins = (const float*)d_in[13];
  const float* b_ins = (const float*)d_in[14];
  float* out = (float*)d_out;

  char* w = (char*)d_ws;
  constexpr size_t CNT_SZ  = 4096;                          // 24 domains x 34
  constexpr size_t TOK_SZ  = (size_t)SX_ * B_ * 4;
  constexpr size_t WCAT_SZ = (size_t)160 * 1024;            // head W fp8
  constexpr size_t W8F_SZ  = (size_t)2048 * 512;            // fwd Whh fp8
  constexpr size_t W8M_SZ  = (size_t)4096 * 1024;           // mod Whh fp8
  constexpr size_t EF_SZ   = (size_t)67 * 2048 * 4;         // E tables f32
  constexpr size_t EM_SZ   = (size_t)67 * 4096 * 4;
  constexpr size_t LX_SZ   = (size_t)SX_ * B_ * OP_ * 4;
  constexpr size_t HF_SZ   = (size_t)35 * B_ * 512;         // h slabs fp8
  constexpr size_t HM_SZ   = (size_t)35 * B_ * 1024;

  size_t off = 0;
  unsigned* cnt = (unsigned*)(w + off); off += CNT_SZ;
  int*  tok_x   = (int*)(w + off);  off += TOK_SZ;
  int*  tok_y   = (int*)(w + off);  off += TOK_SZ;
  off = (off + 255) & ~(size_t)255;
  u8*   Wcat    = (u8*)(w + off);   off += WCAT_SZ;
  u8*   w8_f    = (u8*)(w + off);   off += W8F_SZ;
  u8*   w8_r    = (u8*)(w + off);   off += W8F_SZ;
  u8*   w8_m    = (u8*)(w + off);   off += W8M_SZ;
  float* E_f    = (float*)(w + off); off += EF_SZ;
  float* E_r    = (float*)(w + off); off += EF_SZ;
  float* E_m    = (float*)(w + off); off += EM_SZ;
  float* lx_sub = (float*)(w + off); off += LX_SZ;
  float* lx_ins = (float*)(w + off); off += LX_SZ;
  float* ly_sub = (float*)(w + off); off += LX_SZ;
  float* ly_ins = (float*)(w + off); off += LX_SZ;
  u8* fwd_all   = (u8*)(w + off);   off += HF_SZ;
  u8* rev_all   = (u8*)(w + off);   off += HF_SZ;
  u8* y_all     = (u8*)(w + off);   off += HM_SZ;
  (void)ws_size; (void)in_sizes; (void)n_in; (void)out_size;

  // zero: barrier counters + t=0 h slabs
  (void)hipMemsetAsync(cnt, 0, CNT_SZ, stream);
  (void)hipMemsetAsync(fwd_all, 0, (size_t)B_ * 512, stream);
  (void)hipMemsetAsync(rev_all, 0, (size_t)B_ * 512, stream);
  (void)hipMemsetAsync(y_all,   0, (size_t)B_ * 1024, stream);

  decode_tokens<<<(2 * SX_ * B_ + 255) / 256, 256, 0, stream>>>(sources, targets, tok_x, tok_y);
  pad_head_w<<<160, 256, 0, stream>>>(W_sub, W_ins, Wcat);
  conv_fp8<<<1024, 256, 0, stream>>>(Whh_f, w8_f, 2048 * 512 / 4);
  conv_fp8<<<1024, 256, 0, stream>>>(Whh_r, w8_r, 2048 * 512 / 4);
  conv_fp8<<<2048, 256, 0, stream>>>(Whh_m, w8_m, 4096 * 1024 / 4);
  build_E<<<(67 * 2048 + 255) / 256, 256, 0, stream>>>(Wih_f, b_f, E_f, 11);
  build_E<<<(67 * 2048 + 255) / 256, 256, 0, stream>>>(Wih_r, b_r, E_r, 11);
  build_E<<<(67 * 4096 + 255) / 256, 256, 0, stream>>>(Wih_m, b_m, E_m, 12);

  lstm_persist<<<256, 256, 0, stream>>>(
      tok_x, tok_y,
      E_f, w8_f,
      E_r, w8_r,
      E_m, w8_m,
      fwd_all, rev_all, y_all, cnt);

  head_kernel<<<136, 256, 0, stream>>>(fwd_all, rev_all, y_all, Wcat,
                                       b_sub, b_ins, lx_sub, lx_ins, ly_sub, ly_ins);

  pair_kernel<<<136, 256, 0, stream>>>(tok_x, tok_y, lx_sub, lx_ins,
                                       ly_sub, ly_ins, out);
}

// Round 7
// 460.776 us; speedup vs baseline: 4.4943x; 1.0343x over previous
//
#include <hip/hip_runtime.h>

typedef __attribute__((ext_vector_type(4))) float f32x4;
typedef unsigned char u8;
typedef unsigned long long u64t;

#define BIG_NEG -1000000000.0f

static constexpr int B_  = 256;
static constexpr int SX_ = 34;
static constexpr int SY_ = 34;
static constexpr int IND = 66;   // IN_DIM
static constexpr int OP_ = 80;   // padded OUT_DIM (65 -> 80)

__device__ __forceinline__ f32x4 mfma_fp8(long a, long b, f32x4 c) {
  return __builtin_amdgcn_mfma_f32_16x16x32_fp8_fp8(a, b, c, 0, 0, 0);
}
__device__ __forceinline__ float sigm(float x)  { return 1.0f / (1.0f + __expf(-x)); }
__device__ __forceinline__ float tanhx(float x) { return 2.0f * sigm(2.0f * x) - 1.0f; }
template <bool HI>
__device__ __forceinline__ unsigned pk2(float a, float b, unsigned old) {
  return __builtin_amdgcn_cvt_pk_fp8_f32(a, b, (int)old, HI);
}

// ---------------------------------------------------------------------------
// prep kernels
// ---------------------------------------------------------------------------
__global__ void decode_tokens(const float* __restrict__ src,
                              const float* __restrict__ tgt,
                              int* __restrict__ tok_x, int* __restrict__ tok_y) {
  int idx = blockIdx.x * 256 + threadIdx.x;
  const int half = SX_ * B_;
  if (idx >= 2 * half) return;
  const float* base = (idx < half) ? src : tgt;
  int* outp         = (idx < half) ? tok_x : tok_y;
  int k = (idx < half) ? idx : idx - half;
  const float* p = base + (size_t)k * IND;
  int tok = -1;
  for (int v = 0; v < IND; ++v) if (p[v] > 0.5f) tok = v;
  outp[k] = tok;
}

// all three Whh -> fp8, one launch (grid-stride over 4B words = 4 floats)
__global__ void conv_fp8_all(const float* __restrict__ Wf, const float* __restrict__ Wr,
                             const float* __restrict__ Wm,
                             u8* __restrict__ of, u8* __restrict__ orr, u8* __restrict__ om) {
  const int F4 = 2048 * 512 / 4;
  const int M4 = 4096 * 1024 / 4;
  int i = blockIdx.x * 256 + threadIdx.x;
  int stride = gridDim.x * 256;
  for (; i < 2 * F4 + M4; i += stride) {
    const float* src; unsigned* dst; int k;
    if (i < F4)          { src = Wf; dst = (unsigned*)of;  k = i; }
    else if (i < 2 * F4) { src = Wr; dst = (unsigned*)orr; k = i - F4; }
    else                 { src = Wm; dst = (unsigned*)om;  k = i - 2 * F4; }
    float4 f = ((const float4*)src)[k];
    unsigned w = pk2<false>(f.x, f.y, 0);
    w = pk2<true>(f.z, f.w, w);
    dst[k] = w;
  }
}

// E[v][n] = (v<66 ? Wih[n][v] : 0) + bias[n]  — LDS-tiled transpose, all 3 models.
// 128 blocks: [0,32) fwd, [32,64) rev, [64,128) mod; each block one 64-n tile.
__global__ __launch_bounds__(256) void build_E_all(
    const float* __restrict__ Wf, const float* __restrict__ bf,
    const float* __restrict__ Wr, const float* __restrict__ br,
    const float* __restrict__ Wm, const float* __restrict__ bm,
    float* __restrict__ Ef, float* __restrict__ Er, float* __restrict__ Em) {
  __shared__ float tile[64 * 67];
  int tb = blockIdx.x;
  const float* W; const float* bias; float* E; int H4; int n0;
  if (tb < 32)      { W = Wf; bias = bf; E = Ef; H4 = 2048; n0 = tb * 64; }
  else if (tb < 64) { W = Wr; bias = br; E = Er; H4 = 2048; n0 = (tb - 32) * 64; }
  else              { W = Wm; bias = bm; E = Em; H4 = 4096; n0 = (tb - 64) * 64; }
  const float* src = W + (size_t)n0 * IND;
  for (int i = threadIdx.x; i < 64 * IND; i += 256) {
    int n = i / IND, v = i - n * IND;
    tile[n * 67 + v] = src[i];
  }
  __syncthreads();
  int lane = threadIdx.x & 63, w = threadIdx.x >> 6;
  float bl = bias[n0 + lane];
  for (int v = w; v < 67; v += 4) {
    float val = (v < 66 ? tile[lane * 67 + v] : 0.f) + bl;
    E[(size_t)v * H4 + n0 + lane] = val;
  }
}

// Wcat: fp8 [160][1024]; rows 0..79 = W_sub (padded), 80..159 = W_ins
__global__ void pad_head_w(const float* __restrict__ Wsub, const float* __restrict__ Wins,
                           u8* __restrict__ Wcat) {
  int widx = blockIdx.x * 256 + threadIdx.x;  // one 4-byte word
  if (widx >= 160 * 256) return;
  int row = widx >> 8;
  int wc  = widx & 255;
  int srow = row < 80 ? row : row - 80;
  const float* W = row < 80 ? Wsub : Wins;
  float f0 = 0.f, f1 = 0.f, f2 = 0.f, f3 = 0.f;
  if (srow < 65) {
    const float* p = W + (size_t)srow * 1024 + wc * 4;
    f0 = p[0]; f1 = p[1]; f2 = p[2]; f3 = p[3];
  }
  unsigned w = pk2<false>(f0, f1, 0);
  w = pk2<true>(f2, f3, w);
  ((unsigned*)Wcat)[widx] = w;
}

// ---------------------------------------------------------------------------
// persistent LSTM: 256 blocks x 256 thr (1/CU), NO fences, NO atomic RMW.
// Block = (batch chunk of 32) x (64 h-units, all 4 gates). ALL Whh weights
// VGPR-resident (fwd/rev 128 VGPR, mod 256 VGPR; 1 wave/SIMD).
// Barrier: per-block flag store (128B-spread) + parallel-lane poll + ballot.
// ---------------------------------------------------------------------------
template <int HH, int NS>
__device__ __forceinline__ void run_lstm(
    const u8* __restrict__ w8, const float* __restrict__ E,
    bool revr, u8* __restrict__ hall, int b0, int h0,
    unsigned* __restrict__ flags, int dom0, int myid,
    u8* __restrict__ alds, u8* __restrict__ hT, const u8* __restrict__ tok_small) {
  const int tid = threadIdx.x;
  const int lane = tid & 63, w = tid >> 6;
  const int lo = lane & 15, q = lane >> 4;
  constexpr int AST = HH + 8;          // padded LDS row stride (bytes)
  constexpr int U8C = HH / 8;
  constexpr int USH = (HH == 1024) ? 7 : 6;
  constexpr int NI  = (32 * U8C) / 256;   // 8 (fwd/rev) or 16 (mod)
  constexpr int NK  = HH / 32;
  const int hu = h0 + w * 16 + lo;     // this lane's h-unit

  long breg[4][NK];                    // ALL K resident in VGPRs
#pragma unroll
  for (int g = 0; g < 4; ++g) {
    const u8* brow = w8 + (size_t)(g * HH + hu) * HH + q * 8;
#pragma unroll
    for (int kk = 0; kk < NK; ++kk)
      breg[g][kk] = *(const long*)(brow + kk * 32);
  }
  float creg[8] = {0.f, 0.f, 0.f, 0.f, 0.f, 0.f, 0.f, 0.f};

  for (int t = 0; t < 34; ++t) {
    // ---- stage A-tile: batched relaxed-atomic loads -> regs -> LDS ----
    const u8* hsrc = hall + (size_t)t * (256 * HH);
    u64t tmp[NI];
#pragma unroll
    for (int ii = 0; ii < NI; ++ii) {
      int idx = tid + ii * 256;
      tmp[ii] = __hip_atomic_load(
          (const u64t*)(hsrc + (size_t)(b0 + (idx >> USH)) * HH + (idx & (U8C - 1)) * 8),
          __ATOMIC_RELAXED, __HIP_MEMORY_SCOPE_AGENT);
    }
#pragma unroll
    for (int ii = 0; ii < NI; ++ii) {
      int idx = tid + ii * 256;
      *(u64t*)&alds[(idx >> USH) * AST + (idx & (U8C - 1)) * 8] = tmp[ii];
    }
    __syncthreads();

    f32x4 acc[2][4];
#pragma unroll
    for (int mt = 0; mt < 2; ++mt)
#pragma unroll
      for (int g = 0; g < 4; ++g) acc[mt][g] = (f32x4){0.f, 0.f, 0.f, 0.f};

    const u8* a0p = alds + lo * AST + q * 8;
    const u8* a1p = alds + (16 + lo) * AST + q * 8;
#pragma unroll
    for (int kk = 0; kk < NK; ++kk) {
      long a0 = *(const long*)(a0p + kk * 32);
      long a1 = *(const long*)(a1p + kk * 32);
#pragma unroll
      for (int g = 0; g < 4; ++g) {
        acc[0][g] = mfma_fp8(a0, breg[g][kk], acc[0][g]);
        acc[1][g] = mfma_fp8(a1, breg[g][kk], acc[1][g]);
      }
    }

    // ---- epilogue: E-gather + gate math; pack fp8 into hT (LDS) ----
    int tpos = revr ? 33 - t : t;
    const u8* tkp = tok_small + tpos * 32;
#pragma unroll
    for (int mt = 0; mt < 2; ++mt) {
      float hv[4];
#pragma unroll
      for (int r = 0; r < 4; ++r) {
        int m = mt * 16 + q * 4 + r;
        int v = tkp[m];
        const float* e = E + (size_t)v * (4 * HH) + hu;
        float g4[4];
#pragma unroll
        for (int g = 0; g < 4; ++g) g4[g] = acc[mt][g][r] + e[g * HH];
        float cold = creg[mt * 4 + r];
        float cn = sigm(g4[1]) * cold + sigm(g4[0]) * tanhx(g4[2]);
        hv[r] = sigm(g4[3]) * tanhx(cn);
        creg[mt * 4 + r] = cn;
      }
      unsigned pw = pk2<false>(hv[0], hv[1], 0);
      pw = pk2<true>(hv[2], hv[3], pw);
      *(unsigned*)&hT[(w * 16 + lo) * 36 + mt * 16 + q * 4] = pw;
    }
    __syncthreads();

    // ---- coalesced 8B agent store: thread -> (row m, 8-col chunk cc) ----
    {
      int m = tid >> 3, cc = tid & 7;
      u64t val = 0;
#pragma unroll
      for (int k = 0; k < 8; ++k)
        val |= (u64t)hT[(cc * 8 + k) * 36 + m] << (8 * k);
      u8* hdst = hall + (size_t)(t + 1) * (256 * HH);
      __hip_atomic_store((u64t*)(hdst + (size_t)(b0 + m) * HH + h0 + cc * 8), val,
                         __ATOMIC_RELAXED, __HIP_MEMORY_SCOPE_AGENT);
    }

    // ---- flag barrier: drain stores, fire flag, parallel poll ----
    if (t < 33) {
      __asm__ volatile("s_waitcnt vmcnt(0)" ::: "memory");
      __syncthreads();
      unsigned tgt = (unsigned)(t + 1);
      if (tid == 0)
        __hip_atomic_store(&flags[(dom0 + myid) * 32], tgt,
                           __ATOMIC_RELAXED, __HIP_MEMORY_SCOPE_AGENT);
      if (tid < NS) {
        int spin = 0;
        for (;;) {
          unsigned v = __hip_atomic_load(&flags[(dom0 + tid) * 32],
                                         __ATOMIC_RELAXED, __HIP_MEMORY_SCOPE_AGENT);
          if (__ballot(v < tgt) == 0) break;
          __builtin_amdgcn_s_sleep(1);
          if (++spin > (1 << 16)) break;   // safety exit
        }
      }
      __syncthreads();
    }
  }
}

__global__ __launch_bounds__(256, 1) void lstm_persist(
    const int* __restrict__ tok_x, const int* __restrict__ tok_y,
    const float* __restrict__ E_f, const u8* __restrict__ w8_f,
    const float* __restrict__ E_r, const u8* __restrict__ w8_r,
    const float* __restrict__ E_m, const u8* __restrict__ w8_m,
    u8* __restrict__ fwd_all, u8* __restrict__ rev_all, u8* __restrict__ y_all,
    unsigned* __restrict__ flags) {
  __shared__ u8 alds[32 * 1032];       // 33 KB A-stage (fwd/rev use 32*520)
  __shared__ u8 hT[64 * 36];           // store-transpose buffer
  __shared__ u8 tok_small[34 * 32];    // this block's tokens (66 = none)

  const int b = blockIdx.x;
  int role, c, s;
  if (b < 64)       { role = 0; c = b >> 3; s = b & 7; }
  else if (b < 128) { int l = b - 64;  role = 1; c = l >> 3; s = l & 7; }
  else              { int l = b - 128; role = 2; c = l >> 4; s = l & 15; }

  const float* E  = role == 0 ? E_f  : role == 1 ? E_r  : E_m;
  const u8*    w8 = role == 0 ? w8_f : role == 1 ? w8_r : w8_m;
  u8* hall        = role == 0 ? fwd_all : role == 1 ? rev_all : y_all;
  const int* tokg = (role == 2) ? tok_y : tok_x;
  const int b0 = c * 32;
  const int h0 = s * 64;
  const int dom0 = (role == 0) ? c * 8 : (role == 1) ? 64 + c * 8 : 128 + c * 16;

  for (int i = threadIdx.x; i < 34 * 32; i += 256) {
    int t2 = i >> 5, m = i & 31;
    int tk = tokg[t2 * 256 + b0 + m];
    tok_small[i] = (u8)(tk < 0 ? 66 : tk);
  }
  __syncthreads();

  if (role == 2)
    run_lstm<1024, 16>(w8, E, false, hall, b0, h0, flags, dom0, s, alds, hT, tok_small);
  else
    run_lstm<512, 8>(w8, E, role == 1, hall, b0, h0, flags, dom0, s, alds, hT, tok_small);
}

// ---------------------------------------------------------------------------
// head: lx = x_emb @ W^T, ly = y_emb @ W^T + b, both heads (W rows 0..159).
// 136 blocks x 256 thr; A-loads issued BEFORE W staging (latency overlap).
// ---------------------------------------------------------------------------
__global__ __launch_bounds__(256, 1) void head_kernel(
    const u8* __restrict__ fwd_all, const u8* __restrict__ rev_all,
    const u8* __restrict__ y_all, const u8* __restrict__ Wcat,
    const float* __restrict__ b_sub, const float* __restrict__ b_ins,
    float* __restrict__ lx_sub, float* __restrict__ lx_ins,
    float* __restrict__ ly_sub, float* __restrict__ ly_ins) {
  __shared__ u8 wq[160 * 264];   // 42240 B, row pad 264 for bank spread
  const int lane = threadIdx.x & 63, wave = threadIdx.x >> 6;
  const int lo = lane & 15, q = lane >> 4;
  int blk = blockIdx.x;
  bool yside = (blk >= 68);
  int mb = yside ? blk - 68 : blk;
  int ij = mb >> 1;
  int bbase = (mb & 1) * 128;

  f32x4 acc[2][10];
#pragma unroll
  for (int mt = 0; mt < 2; ++mt)
#pragma unroll
    for (int nn = 0; nn < 10; ++nn) acc[mt][nn] = (f32x4){0.f,0.f,0.f,0.f};

  for (int qk = 0; qk < 4; ++qk) {
    // A-fragment loads first (independent of LDS) -> overlap with staging
    long aA[2][8];
#pragma unroll
    for (int mt = 0; mt < 2; ++mt) {
      int row = bbase + wave * 32 + mt * 16 + lo;
      const u8* ab;
      if (yside)
        ab = y_all + ((size_t)(ij + 1) * 256 + row) * 1024 + qk * 256 + q * 8;
      else if (qk < 2)
        ab = fwd_all + ((size_t)(ij + 1) * 256 + row) * 512 + qk * 256 + q * 8;
      else
        ab = rev_all + ((size_t)(34 - ij) * 256 + row) * 512 + (qk - 2) * 256 + q * 8;
#pragma unroll
      for (int ki = 0; ki < 8; ++ki) aA[mt][ki] = *(const long*)(ab + ki * 32);
    }

    for (int c8 = threadIdx.x; c8 < 160 * 32; c8 += 256) {
      int row = c8 >> 5, col = (c8 & 31) << 3;
      *(long*)&wq[row * 264 + col] =
          *(const long*)&Wcat[(size_t)row * 1024 + qk * 256 + col];
    }
    __syncthreads();

#pragma unroll
    for (int ki = 0; ki < 8; ++ki) {
#pragma unroll
      for (int nn = 0; nn < 10; ++nn) {
        long bf = *(const long*)&wq[(nn * 16 + lo) * 264 + ki * 32 + q * 8];
        acc[0][nn] = mfma_fp8(aA[0][ki], bf, acc[0][nn]);
        acc[1][nn] = mfma_fp8(aA[1][ki], bf, acc[1][nn]);
      }
    }
    __syncthreads();
  }

#pragma unroll
  for (int mt = 0; mt < 2; ++mt) {
#pragma unroll
    for (int nn = 0; nn < 10; ++nn) {
      bool is_sub = (nn < 5);
      int n = (is_sub ? nn : nn - 5) * 16 + lo;
      float bias = 0.0f;
      if (yside && n < 65) bias = is_sub ? b_sub[n] : b_ins[n];
      float* dst = yside ? (is_sub ? ly_sub : ly_ins) : (is_sub ? lx_sub : lx_ins);
#pragma unroll
      for (int r = 0; r < 4; ++r) {
        int b = bbase + wave * 32 + mt * 16 + q * 4 + r;
        dst[((size_t)ij * 256 + b) * OP_ + n] = acc[mt][nn][r] + bias;
      }
    }
  }
}

// ---------------------------------------------------------------------------
// pair: per (i,j,b) logsumexp over 65 of lx+ly for both heads.
// 136 blocks (34 i x 4 b-chunks) x 256 thr (64 b x 4 j-lanes); lx in regs.
// ---------------------------------------------------------------------------
__device__ __forceinline__ void lse_regs(const float4* __restrict__ X,
                                         const float* __restrict__ py, int sym,
                                         float& logZ, float& v64, float& vs) {
  const float4* py4 = (const float4*)py;
  float4 Y[17];
#pragma unroll
  for (int q = 0; q < 17; ++q) Y[q] = py4[q];
  float mm = -3.4e38f;
#pragma unroll
  for (int q = 0; q < 17; ++q) {
    float vx[4] = {X[q].x + Y[q].x, X[q].y + Y[q].y, X[q].z + Y[q].z, X[q].w + Y[q].w};
#pragma unroll
    for (int c = 0; c < 4; ++c) {
      int o = q * 4 + c;
      if (o < 65) mm = fmaxf(mm, vx[c]);
    }
  }
  float ss = 0.f, vsl = 0.f, vend = 0.f;
#pragma unroll
  for (int q = 0; q < 17; ++q) {
    float vx[4] = {X[q].x + Y[q].x, X[q].y + Y[q].y, X[q].z + Y[q].z, X[q].w + Y[q].w};
#pragma unroll
    for (int c = 0; c < 4; ++c) {
      int o = q * 4 + c;
      if (o < 65) {
        ss += __expf(vx[c] - mm);
        if (o == 64) vend = vx[c];
        if (o == sym) vsl = vx[c];
      }
    }
  }
  logZ = mm + __logf(ss);
  v64 = vend;
  vs = vsl;
}

__global__ __launch_bounds__(256, 1) void pair_kernel(
    const int* __restrict__ tok_x, const int* __restrict__ tok_y,
    const float* __restrict__ lx_sub, const float* __restrict__ lx_ins,
    const float* __restrict__ ly_sub, const float* __restrict__ ly_ins,
    float* __restrict__ out) {
  const int i = blockIdx.x >> 2;
  const int bc = blockIdx.x & 3;
  const int jq = threadIdx.x >> 6;
  const int bl = threadIdx.x & 63;
  const int b = bc * 64 + bl;
  const size_t CH = (size_t)SX_ * SY_ * B_;

  float4 Xs[17], Xi[17];
  {
    const float4* ps = (const float4*)(lx_sub + ((size_t)i * 256 + b) * OP_);
    const float4* pi = (const float4*)(lx_ins + ((size_t)i * 256 + b) * OP_);
#pragma unroll
    for (int q = 0; q < 17; ++q) { Xs[q] = ps[q]; Xi[q] = pi[q]; }
  }
  int tx = tok_x[i * 256 + b];

  for (int j = jq; j < 34; j += 4) {
    size_t obase = ((size_t)i * SY_ + j) * 256 + b;
    bool dead = (j == SY_ - 1) || (tx < 0);
    if (!dead) {
      int ty = tok_y[j * 256 + b];
      if (ty < 0) dead = true;
    }
    if (dead) {
      out[obase] = BIG_NEG;
      out[CH + obase] = BIG_NEG;
      out[2 * CH + obase] = BIG_NEG;
      out[3 * CH + obase] = BIG_NEG;
      continue;
    }
    int tn = tok_y[(j + 1) * 256 + b];
    bool ins_ok = (tn != 65);
    int sym = (tn >= 0 && tn < 64) ? tn : -1;

    float logZs, v64s, vss;
    lse_regs(Xs, ly_sub + ((size_t)j * 256 + b) * OP_, sym, logZs, v64s, vss);
    float dlt = v64s - logZs;
    float sub_val = (sym >= 0) ? (vss - logZs) : 0.0f;

    float logZi, v64i, vsi;
    lse_regs(Xi, ly_ins + ((size_t)j * 256 + b) * OP_, sym, logZi, v64i, vsi);
    float endv = v64i - logZi;
    float ins_val = (sym >= 0) ? (vsi - logZi) : 0.0f;

    out[obase]          = ins_ok ? ins_val : BIG_NEG;
    out[CH + obase]     = ins_ok ? sub_val : BIG_NEG;
    out[2 * CH + obase] = endv;
    out[3 * CH + obase] = dlt;
  }
}

// ---------------------------------------------------------------------------
// launch
// ---------------------------------------------------------------------------
extern "C" void kernel_launch(void* const* d_in, const int* in_sizes, int n_in,
                              void* d_out, int out_size, void* d_ws, size_t ws_size,
                              hipStream_t stream) {
  const float* sources = (const float*)d_in[0];
  const float* targets = (const float*)d_in[1];
  const float* Wih_f = (const float*)d_in[2];
  const float* Whh_f = (const float*)d_in[3];
  const float* b_f   = (const float*)d_in[4];
  const float* Wih_r = (const float*)d_in[5];
  const float* Whh_r = (const float*)d_in[6];
  const float* b_r   = (const float*)d_in[7];
  const float* Wih_m = (const float*)d_in[8];
  const float* Whh_m = (const float*)d_in[9];
  const float* b_m   = (const float*)d_in[10];
  const float* W_sub = (const float*)d_in[11];
  const float* b_sub = (const float*)d_in[12];
  const float* W_ins = (const float*)d_in[13];
  const float* b_ins = (const float*)d_in[14];
  float* out = (float*)d_out;

  char* w = (char*)d_ws;
  constexpr size_t FLAG_SZ = 256 * 32 * 4;                  // 32 KB, 128B-spread
  constexpr size_t TOK_SZ  = (size_t)SX_ * B_ * 4;
  constexpr size_t WCAT_SZ = (size_t)160 * 1024;            // head W fp8
  constexpr size_t W8F_SZ  = (size_t)2048 * 512;            // fwd Whh fp8
  constexpr size_t W8M_SZ  = (size_t)4096 * 1024;           // mod Whh fp8
  constexpr size_t EF_SZ   = (size_t)67 * 2048 * 4;         // E tables f32
  constexpr size_t EM_SZ   = (size_t)67 * 4096 * 4;
  constexpr size_t LX_SZ   = (size_t)SX_ * B_ * OP_ * 4;
  constexpr size_t HF_SZ   = (size_t)35 * B_ * 512;         // h slabs fp8
  constexpr size_t HM_SZ   = (size_t)35 * B_ * 1024;

  size_t off = 0;
  unsigned* flags = (unsigned*)(w + off); off += FLAG_SZ;
  int*  tok_x   = (int*)(w + off);  off += TOK_SZ;
  int*  tok_y   = (int*)(w + off);  off += TOK_SZ;
  off = (off + 255) & ~(size_t)255;
  u8*   Wcat    = (u8*)(w + off);   off += WCAT_SZ;
  u8*   w8_f    = (u8*)(w + off);   off += W8F_SZ;
  u8*   w8_r    = (u8*)(w + off);   off += W8F_SZ;
  u8*   w8_m    = (u8*)(w + off);   off += W8M_SZ;
  float* E_f    = (float*)(w + off); off += EF_SZ;
  float* E_r    = (float*)(w + off); off += EF_SZ;
  float* E_m    = (float*)(w + off); off += EM_SZ;
  float* lx_sub = (float*)(w + off); off += LX_SZ;
  float* lx_ins = (float*)(w + off); off += LX_SZ;
  float* ly_sub = (float*)(w + off); off += LX_SZ;
  float* ly_ins = (float*)(w + off); off += LX_SZ;
  u8* fwd_all   = (u8*)(w + off);   off += HF_SZ;
  u8* rev_all   = (u8*)(w + off);   off += HF_SZ;
  u8* y_all     = (u8*)(w + off);   off += HM_SZ;
  (void)ws_size; (void)in_sizes; (void)n_in; (void)out_size;

  // zero: flags + t=0 h slabs
  (void)hipMemsetAsync(flags, 0, FLAG_SZ, stream);
  (void)hipMemsetAsync(fwd_all, 0, (size_t)B_ * 512, stream);
  (void)hipMemsetAsync(rev_all, 0, (size_t)B_ * 512, stream);
  (void)hipMemsetAsync(y_all,   0, (size_t)B_ * 1024, stream);

  decode_tokens<<<(2 * SX_ * B_ + 255) / 256, 256, 0, stream>>>(sources, targets, tok_x, tok_y);
  pad_head_w<<<160, 256, 0, stream>>>(W_sub, W_ins, Wcat);
  conv_fp8_all<<<3072, 256, 0, stream>>>(Whh_f, Whh_r, Whh_m, w8_f, w8_r, w8_m);
  build_E_all<<<128, 256, 0, stream>>>(Wih_f, b_f, Wih_r, b_r, Wih_m, b_m, E_f, E_r, E_m);

  lstm_persist<<<256, 256, 0, stream>>>(
      tok_x, tok_y,
      E_f, w8_f,
      E_r, w8_r,
      E_m, w8_m,
      fwd_all, rev_all, y_all, flags);

  head_kernel<<<136, 256, 0, stream>>>(fwd_all, rev_all, y_all, Wcat,
                                       b_sub, b_ins, lx_sub, lx_ins, ly_sub, ly_ins);

  pair_kernel<<<136, 256, 0, stream>>>(tok_x, tok_y, lx_sub, lx_ins,
                                       ly_sub, ly_ins, out);
}